// Round 2
// baseline (741.007 us; speedup 1.0000x reference)
//
#include <hip/hip_runtime.h>

// ---------------------------------------------------------------------------
// ConvLinformerSelfAttention on MI355X (gfx950), bf16 MFMA pipeline.
// Stages:
//  1. k_reorder_wpk : Wpk(256,4096,32) f32 -> Wr(32,256,4096) bf16
//  2. k_init_kc     : Kc(4,256,1024) f32 = bpk[k]
//  3. k_gemm_qk     : [Q|Kp] = x @ [Wq|Wk]^T   (bf16 out)
//  4. k_transpose   : Kp(4,4096,1024) -> KpT(4,1024,4096)
//  5. k_conv        : Kc += sum_t Wr[t] @ shifted(KpT)   (split-K atomics)
//  6. k_kc_post     : Kcbf(4,256,1024), KcT(4,1024,256) bf16
//  7. k_attn        : per (b,h): softmax(Q K^T / sqrt(128)) @ V -> AO
//  8. k_gemm_out    : out = AO @ Wo^T + bo  (FLOAT32 out — ref output dtype)
// ---------------------------------------------------------------------------

typedef short v8s __attribute__((ext_vector_type(8)));   // 8 x bf16 bits
typedef float v4f __attribute__((ext_vector_type(4)));

#define MFMA16(a, b, c) __builtin_amdgcn_mfma_f32_16x16x32_bf16((a), (b), (c), 0, 0, 0)

__device__ __forceinline__ unsigned short f2bf(float f) {
  unsigned int u = __float_as_uint(f);
  u += 0x7fffu + ((u >> 16) & 1u);   // round-to-nearest-even
  return (unsigned short)(u >> 16);
}

__device__ __forceinline__ v8s cvt8(float4 a, float4 b) {
  v8s v;
  v[0] = (short)f2bf(a.x); v[1] = (short)f2bf(a.y);
  v[2] = (short)f2bf(a.z); v[3] = (short)f2bf(a.w);
  v[4] = (short)f2bf(b.x); v[5] = (short)f2bf(b.y);
  v[6] = (short)f2bf(b.z); v[7] = (short)f2bf(b.w);
  return v;
}

// --------------------------------------------------------------- 1. reorder
// Wpk (k,n,t) f32 -> Wr (t,k,n) bf16.  grid 16384 (k*64 + ntile), 256 thr.
__global__ __launch_bounds__(256) void k_reorder_wpk(const float* __restrict__ Wpk,
                                                     short* __restrict__ Wr) {
  __shared__ short T[64][40];  // [n_local][t], 80B rows
  const int k  = blockIdx.x >> 6;
  const int n0 = (blockIdx.x & 63) << 6;
  const int tid = threadIdx.x;
  {
    const int i = tid >> 2, t0 = (tid & 3) << 3;
    const float* p = Wpk + ((size_t)k * 4096 + n0 + i) * 32 + t0;
    float4 a = *(const float4*)p, b = *(const float4*)(p + 4);
    *(v8s*)&T[i][t0] = cvt8(a, b);
  }
  __syncthreads();
  {
    const int t = tid >> 3, j0 = (tid & 7) << 3;
    v8s o;
#pragma unroll
    for (int q = 0; q < 8; ++q) o[q] = T[j0 + q][t];
    *(v8s*)(Wr + ((size_t)t * 256 + k) * 4096 + n0 + j0) = o;
  }
}

// --------------------------------------------------------------- 2. init Kc
__global__ __launch_bounds__(256) void k_init_kc(const float* __restrict__ bpk,
                                                 float* __restrict__ Kc) {
  const int idx = (blockIdx.x * 256 + threadIdx.x) * 4;  // < 4*256*1024
  const float v = bpk[(idx >> 10) & 255];
  float4 f; f.x = v; f.y = v; f.z = v; f.w = v;
  *(float4*)(Kc + idx) = f;
}

// --------------------------------------------------------------- 3. QK GEMM
// [Q|Kp](16384 x 2048) = x(16384x1024) @ [Wq|Wk]^T.  grid (128,16), 256 thr.
__global__ __launch_bounds__(256) void k_gemm_qk(const float* __restrict__ x,
                                                 const float* __restrict__ Wq,
                                                 const float* __restrict__ Wk,
                                                 short* __restrict__ Qbf,
                                                 short* __restrict__ Kp) {
  __shared__ short As[128][40];
  __shared__ short Bs[128][40];  // Bs[j][k] = W[j0+j][k0+k]
  const int tid = threadIdx.x;
  const int m0 = blockIdx.x * 128;
  const int j0 = blockIdx.y * 128;
  const int lane = tid & 63, w = tid >> 6;
  const int wr = (w >> 1) * 64, wc = (w & 1) * 64;
  const int l15 = lane & 15, lg8 = (lane >> 4) * 8;

  v4f acc[4][4];
#pragma unroll
  for (int i = 0; i < 4; ++i)
#pragma unroll
    for (int j = 0; j < 4; ++j) acc[i][j] = (v4f)0.0f;

  for (int k0 = 0; k0 < 1024; k0 += 32) {
#pragma unroll
    for (int c = 0; c < 2; ++c) {
      const int cid = tid + (c << 8);          // 0..511
      const int r = cid >> 2, sg = (cid & 3) << 3;
      const float* pa = x + (size_t)(m0 + r) * 1024 + k0 + sg;
      *(v8s*)&As[r][sg] = cvt8(*(const float4*)pa, *(const float4*)(pa + 4));
      const int J = j0 + r;
      const float* pb = (J < 1024 ? Wq + (size_t)J * 1024
                                  : Wk + (size_t)(J - 1024) * 1024) + k0 + sg;
      *(v8s*)&Bs[r][sg] = cvt8(*(const float4*)pb, *(const float4*)(pb + 4));
    }
    __syncthreads();
    v8s af[4], bfr[4];
#pragma unroll
    for (int mi = 0; mi < 4; ++mi) af[mi] = *(const v8s*)&As[wr + mi * 16 + l15][lg8];
#pragma unroll
    for (int ni = 0; ni < 4; ++ni) bfr[ni] = *(const v8s*)&Bs[wc + ni * 16 + l15][lg8];
#pragma unroll
    for (int ni = 0; ni < 4; ++ni)
#pragma unroll
      for (int mi = 0; mi < 4; ++mi)
        acc[mi][ni] = MFMA16(af[mi], bfr[ni], acc[mi][ni]);
    __syncthreads();
  }
  const int rbase = (lane >> 4) * 4;
#pragma unroll
  for (int mi = 0; mi < 4; ++mi)
#pragma unroll
    for (int ni = 0; ni < 4; ++ni) {
      const int col = j0 + wc + ni * 16 + l15;
      short* dst = (col < 1024) ? Qbf : Kp;
      const int cj = (col < 1024) ? col : col - 1024;
#pragma unroll
      for (int r = 0; r < 4; ++r) {
        const int row = m0 + wr + mi * 16 + rbase + r;
        dst[(size_t)row * 1024 + cj] = (short)f2bf(acc[mi][ni][r]);
      }
    }
}

// --------------------------------------------------------------- 4. transpose
// src[NB][R][C] -> dst[NB][C][R], 64x64 tiles. grid (R/64, C/64, NB).
__global__ __launch_bounds__(256) void k_transpose(const short* __restrict__ src,
                                                   short* __restrict__ dst,
                                                   int R, int C) {
  __shared__ short T[64][72];   // 144B rows (16B-aligned)
  const int r0 = blockIdx.x * 64, c0 = blockIdx.y * 64;
  const size_t sb = (size_t)blockIdx.z * R * C;
  const int tid = threadIdx.x;
  {
    const int i = tid >> 2, q = (tid & 3) << 4;
    const short* ps = src + sb + (size_t)(r0 + i) * C + c0 + q;
    *(v8s*)&T[i][q]     = *(const v8s*)ps;
    *(v8s*)&T[i][q + 8] = *(const v8s*)(ps + 8);
  }
  __syncthreads();
  {
    const int j = tid >> 2, p = (tid & 3) << 4;
    v8s o0, o1;
#pragma unroll
    for (int t = 0; t < 8; ++t) o0[t] = T[p + t][j];
#pragma unroll
    for (int t = 0; t < 8; ++t) o1[t] = T[p + 8 + t][j];
    short* pd = dst + sb + (size_t)(c0 + j) * R + r0 + p;
    *(v8s*)pd = o0;
    *(v8s*)(pd + 8) = o1;
  }
}

// --------------------------------------------------------------- 5. conv GEMM
// Kc[b][kch][d] += sum_{t,n} Wr[t][kch][n] * KpT[b][d+t-15][n]
// grid 512 = mt(2) x nt(8) x ns(8) x b(4); 256 thr; split-K atomics.
__global__ __launch_bounds__(256) void k_conv(const short* __restrict__ Wr,
                                              const short* __restrict__ KpT,
                                              float* __restrict__ Kc) {
  __shared__ short Kt[159][40];      // halo'd KpT slice [d'][n_local]
  __shared__ short As[4][128][40];   // 4 t-planes of Wr    [t][kch][n_local]
  const int bx = blockIdx.x;
  const int b = bx & 3, ns = (bx >> 2) & 7, nt = (bx >> 5) & 7, mt = bx >> 8;
  const int K0 = mt * 128, D0 = nt * 128;
  const int tid = threadIdx.x;
  const int lane = tid & 63, w = tid >> 6;
  const int wr = (w >> 1) * 64, wc = (w & 1) * 64;
  const int l15 = lane & 15, lg8 = (lane >> 4) * 8;
  const size_t kpt_b = (size_t)b * 1024 * 4096;

  v4f acc[4][4];
#pragma unroll
  for (int i = 0; i < 4; ++i)
#pragma unroll
    for (int j = 0; j < 4; ++j) acc[i][j] = (v4f)0.0f;

#pragma unroll 1
  for (int nc = 0; nc < 16; ++nc) {
    const int n0 = ns * 512 + nc * 32;
    __syncthreads();  // previous iter's Kt reads done
    // stage Kt: 159 rows x 4 segs = 636 x 16B slots, zero-filled halo
#pragma unroll
    for (int it = 0; it < 3; ++it) {
      const int s = it * 256 + tid;
      if (s < 636) {
        const int r = s >> 2, sg = (s & 3) << 3;
        const int dp = D0 - 15 + r;
        v8s v = {0, 0, 0, 0, 0, 0, 0, 0};
        if (dp >= 0 && dp < 1024)
          v = *(const v8s*)(KpT + kpt_b + (size_t)dp * 4096 + n0 + sg);
        *(v8s*)&Kt[r][sg] = v;
      }
    }
#pragma unroll 1
    for (int tc = 0; tc < 8; ++tc) {
      const int t0 = tc * 4;
      __syncthreads();  // prev MFMA reads done (and Kt visible at tc==0)
#pragma unroll
      for (int i = 0; i < 8; ++i) {
        const int s = i * 256 + tid;  // 0..2047
        const int tt = s >> 9, rr = (s >> 2) & 127, sg = (s & 3) << 3;
        *(v8s*)&As[tt][rr][sg] =
            *(const v8s*)(Wr + ((size_t)(t0 + tt) * 256 + K0 + rr) * 4096 + n0 + sg);
      }
      __syncthreads();
#pragma unroll
      for (int tt = 0; tt < 4; ++tt) {
        const int s = t0 + tt;
        v8s af[4], bfr[4];
#pragma unroll
        for (int mi = 0; mi < 4; ++mi)
          af[mi] = *(const v8s*)&As[tt][wr + mi * 16 + l15][lg8];
#pragma unroll
        for (int ni = 0; ni < 4; ++ni)
          bfr[ni] = *(const v8s*)&Kt[wc + ni * 16 + l15 + s][lg8];
#pragma unroll
        for (int ni = 0; ni < 4; ++ni)
#pragma unroll
          for (int mi = 0; mi < 4; ++mi)
            acc[mi][ni] = MFMA16(af[mi], bfr[ni], acc[mi][ni]);
      }
    }
  }
  float* kcb = Kc + (size_t)b * 256 * 1024;
  const int rbase = (lane >> 4) * 4;
#pragma unroll
  for (int mi = 0; mi < 4; ++mi)
#pragma unroll
    for (int ni = 0; ni < 4; ++ni)
#pragma unroll
      for (int r = 0; r < 4; ++r)
        atomicAdd(kcb + (size_t)(K0 + wr + mi * 16 + rbase + r) * 1024 +
                      (D0 + wc + ni * 16 + l15),
                  acc[mi][ni][r]);
}

// --------------------------------------------------------------- 6. Kc post
// Kc f32 -> Kcbf (b,256,1024) bf16 and KcT (b,1024,256) bf16. grid (4,16,4).
__global__ __launch_bounds__(256) void k_kc_post(const float* __restrict__ Kc,
                                                 short* __restrict__ Kcbf,
                                                 short* __restrict__ KcT) {
  __shared__ short T[64][72];
  const int k0 = blockIdx.x * 64, d0 = blockIdx.y * 64, b = blockIdx.z;
  const int tid = threadIdx.x;
  {
    const int i = tid >> 2, q = (tid & 3) << 4;
    const float* ps = Kc + (size_t)(b * 256 + k0 + i) * 1024 + d0 + q;
    float4 f0 = *(const float4*)ps,       f1 = *(const float4*)(ps + 4);
    float4 f2 = *(const float4*)(ps + 8), f3 = *(const float4*)(ps + 12);
    v8s v0 = cvt8(f0, f1), v1 = cvt8(f2, f3);
    *(v8s*)&T[i][q] = v0;
    *(v8s*)&T[i][q + 8] = v1;
    short* pc = Kcbf + (size_t)(b * 256 + k0 + i) * 1024 + d0 + q;
    *(v8s*)pc = v0;
    *(v8s*)(pc + 8) = v1;
  }
  __syncthreads();
  {
    const int j = tid >> 2, p = (tid & 3) << 4;
    v8s o0, o1;
#pragma unroll
    for (int t = 0; t < 8; ++t) o0[t] = T[p + t][j];
#pragma unroll
    for (int t = 0; t < 8; ++t) o1[t] = T[p + 8 + t][j];
    short* pd = KcT + (size_t)(b * 1024 + d0 + j) * 256 + k0 + p;
    *(v8s*)pd = o0;
    *(v8s*)(pd + 8) = o1;
  }
}

// --------------------------------------------------------------- 7. attention
// grid (32 ntiles, 8 heads, 4 batch), 256 thr = 4 waves x 32 q-rows.
__global__ __launch_bounds__(256) void k_attn(const short* __restrict__ Qbf,
                                              const short* __restrict__ Kcbf,
                                              const short* __restrict__ KcT,
                                              short* __restrict__ AO) {
  __shared__ short P[4][16][264];  // per-wave unnormalized softmax tile
  const int nt = blockIdx.x, h = blockIdx.y, b = blockIdx.z;
  const int tid = threadIdx.x, lane = tid & 63, w = tid >> 6;
  const int l15 = lane & 15, lg4 = (lane >> 4) * 4, lg8 = (lane >> 4) * 8;
  const float scale = 0.08838834764831845f;  // 128^-0.5
  const size_t qb  = (size_t)b * 4096 * 1024 + (size_t)h * 128;
  const size_t kb  = (size_t)b * 256 * 1024 + (size_t)h * 128;
  const size_t vtb = ((size_t)b * 1024 + (size_t)h * 128) * 256;
  short (*Pw)[264] = P[w];
  const int n_wave = nt * 128 + w * 32;

#pragma unroll 1
  for (int half = 0; half < 2; ++half) {
    const int nbase = n_wave + half * 16;
    v8s aq[4];
#pragma unroll
    for (int kt = 0; kt < 4; ++kt)
      aq[kt] = *(const v8s*)(Qbf + qb + (size_t)(nbase + l15) * 1024 + kt * 32 + lg8);

    v4f dacc[16];
#pragma unroll
    for (int ct = 0; ct < 16; ++ct) dacc[ct] = (v4f)0.0f;
#pragma unroll 1
    for (int kt = 0; kt < 4; ++kt) {
#pragma unroll
      for (int ct = 0; ct < 16; ++ct) {
        v8s bk = *(const v8s*)(Kcbf + kb + (size_t)(ct * 16 + l15) * 1024 + kt * 32 + lg8);
        dacc[ct] = MFMA16(aq[kt], bk, dacc[ct]);
      }
    }
    // wave-parallel softmax over 256 cols (rows live in reg r + 16-lane group)
#pragma unroll
    for (int ct = 0; ct < 16; ++ct) dacc[ct] = dacc[ct] * scale;
    v4f m4 = dacc[0];
#pragma unroll
    for (int ct = 1; ct < 16; ++ct)
#pragma unroll
      for (int r = 0; r < 4; ++r) m4[r] = fmaxf(m4[r], dacc[ct][r]);
#pragma unroll
    for (int off = 1; off < 16; off <<= 1)
#pragma unroll
      for (int r = 0; r < 4; ++r) m4[r] = fmaxf(m4[r], __shfl_xor(m4[r], off, 64));
    v4f ssum = (v4f)0.0f;
#pragma unroll
    for (int ct = 0; ct < 16; ++ct)
#pragma unroll
      for (int r = 0; r < 4; ++r) {
        const float e = __expf(dacc[ct][r] - m4[r]);
        ssum[r] += e;
        Pw[lg4 + r][ct * 16 + l15] = (short)f2bf(e);
      }
#pragma unroll
    for (int off = 1; off < 16; off <<= 1)
#pragma unroll
      for (int r = 0; r < 4; ++r) ssum[r] += __shfl_xor(ssum[r], off, 64);
    __syncthreads();  // P visible (also orders same-wave write->read)

    v4f oacc[8];
#pragma unroll
    for (int ct = 0; ct < 8; ++ct) oacc[ct] = (v4f)0.0f;
#pragma unroll 1
    for (int kt2 = 0; kt2 < 8; ++kt2) {
      v8s pa = *(const v8s*)&Pw[l15][kt2 * 32 + lg8];
#pragma unroll
      for (int ct = 0; ct < 8; ++ct) {
        v8s bv = *(const v8s*)(KcT + vtb + (size_t)(ct * 16 + l15) * 256 + kt2 * 32 + lg8);
        oacc[ct] = MFMA16(pa, bv, oacc[ct]);
      }
    }
    v4f inv;
#pragma unroll
    for (int r = 0; r < 4; ++r) inv[r] = 1.0f / ssum[r];
#pragma unroll
    for (int ct = 0; ct < 8; ++ct)
#pragma unroll
      for (int r = 0; r < 4; ++r)
        AO[qb + (size_t)(nbase + lg4 + r) * 1024 + ct * 16 + l15] =
            (short)f2bf(oacc[ct][r] * inv[r]);
    __syncthreads();  // before next half overwrites P
  }
}

// --------------------------------------------------------------- 8. out GEMM
// out(16384x1024) = AO @ Wo^T + bo, FLOAT32 out. grid (128, 8), 256 thr.
__global__ __launch_bounds__(256) void k_gemm_out(const short* __restrict__ AO,
                                                  const float* __restrict__ Wo,
                                                  const float* __restrict__ bo,
                                                  float* __restrict__ out) {
  __shared__ short As[128][40];
  __shared__ short Bs[128][40];
  const int tid = threadIdx.x;
  const int m0 = blockIdx.x * 128;
  const int j0 = blockIdx.y * 128;
  const int lane = tid & 63, w = tid >> 6;
  const int wr = (w >> 1) * 64, wc = (w & 1) * 64;
  const int l15 = lane & 15, lg8 = (lane >> 4) * 8;

  v4f acc[4][4];
#pragma unroll
  for (int i = 0; i < 4; ++i)
#pragma unroll
    for (int j = 0; j < 4; ++j) acc[i][j] = (v4f)0.0f;

  for (int k0 = 0; k0 < 1024; k0 += 32) {
#pragma unroll
    for (int c = 0; c < 2; ++c) {
      const int cid = tid + (c << 8);
      const int r = cid >> 2, sg = (cid & 3) << 3;
      *(v8s*)&As[r][sg] = *(const v8s*)(AO + (size_t)(m0 + r) * 1024 + k0 + sg);
      const float* pb = Wo + (size_t)(j0 + r) * 1024 + k0 + sg;
      *(v8s*)&Bs[r][sg] = cvt8(*(const float4*)pb, *(const float4*)(pb + 4));
    }
    __syncthreads();
    v8s af[4], bfr[4];
#pragma unroll
    for (int mi = 0; mi < 4; ++mi) af[mi] = *(const v8s*)&As[wr + mi * 16 + l15][lg8];
#pragma unroll
    for (int ni = 0; ni < 4; ++ni) bfr[ni] = *(const v8s*)&Bs[wc + ni * 16 + l15][lg8];
#pragma unroll
    for (int ni = 0; ni < 4; ++ni)
#pragma unroll
      for (int mi = 0; mi < 4; ++mi)
        acc[mi][ni] = MFMA16(af[mi], bfr[ni], acc[mi][ni]);
    __syncthreads();
  }
  const int rbase = (lane >> 4) * 4;
#pragma unroll
  for (int mi = 0; mi < 4; ++mi)
#pragma unroll
    for (int ni = 0; ni < 4; ++ni) {
      const int col = j0 + wc + ni * 16 + l15;
      const float bias = bo[col];
#pragma unroll
      for (int r = 0; r < 4; ++r) {
        const int row = m0 + wr + mi * 16 + rbase + r;
        out[(size_t)row * 1024 + col] = acc[mi][ni][r] + bias;
      }
    }
}

// ---------------------------------------------------------------------------
extern "C" void kernel_launch(void* const* d_in, const int* in_sizes, int n_in,
                              void* d_out, int out_size, void* d_ws, size_t ws_size,
                              hipStream_t stream) {
  const float* x   = (const float*)d_in[0];
  const float* Wq  = (const float*)d_in[1];
  const float* Wk  = (const float*)d_in[2];
  const float* Wpk = (const float*)d_in[3];
  const float* bpk = (const float*)d_in[4];
  const float* Wo  = (const float*)d_in[5];
  const float* bo  = (const float*)d_in[6];

  // workspace layout (bytes)
  const size_t OFF_WR   = 0;            // 67,108,864  Wr  (32,256,4096) bf16
  const size_t OFF_QBF  = 67108864;     // 33,554,432  Qbf (4,4096,1024) bf16
  const size_t OFF_KP   = 100663296;    // 33,554,432  Kp  (4,4096,1024) bf16 / AO
  const size_t OFF_KPT  = 134217728;    // 33,554,432  KpT (4,1024,4096) bf16
  const size_t OFF_KC   = 167772160;    //  4,194,304  Kc  (4,256,1024) f32
  const size_t OFF_KCBF = 171966464;    //  2,097,152  Kcbf(4,256,1024) bf16
  const size_t OFF_KCT  = 174063616;    //  2,097,152  KcT (4,1024,256) bf16
  const size_t NEED     = 176160768;
  if (ws_size < NEED) return;  // fail loudly (output stays poisoned)

  char* ws = (char*)d_ws;
  short* Wr   = (short*)(ws + OFF_WR);
  short* Qbf  = (short*)(ws + OFF_QBF);
  short* Kp   = (short*)(ws + OFF_KP);
  short* KpT  = (short*)(ws + OFF_KPT);
  float* Kc   = (float*)(ws + OFF_KC);
  short* Kcbf = (short*)(ws + OFF_KCBF);
  short* KcT  = (short*)(ws + OFF_KCT);
  short* AO   = Kp;  // alias: Kp dead after k_conv consumes KpT
  float* outp = (float*)d_out;

  k_reorder_wpk<<<dim3(16384), dim3(256), 0, stream>>>(Wpk, Wr);
  k_init_kc<<<dim3(1024), dim3(256), 0, stream>>>(bpk, Kc);
  k_gemm_qk<<<dim3(128, 16), dim3(256), 0, stream>>>(x, Wq, Wk, Qbf, Kp);
  k_transpose<<<dim3(64, 16, 4), dim3(256), 0, stream>>>(Kp, KpT, 4096, 1024);
  k_conv<<<dim3(512), dim3(256), 0, stream>>>(Wr, KpT, Kc);
  k_kc_post<<<dim3(4, 16, 4), dim3(256), 0, stream>>>(Kc, Kcbf, KcT);
  k_attn<<<dim3(32, 8, 4), dim3(256), 0, stream>>>(Qbf, Kcbf, KcT, AO);
  k_gemm_out<<<dim3(128, 8), dim3(256), 0, stream>>>(AO, Wo, bo, outp);
}

// Round 3
// 643.863 us; speedup vs baseline: 1.1509x; 1.1509x over previous
//
#include <hip/hip_runtime.h>

// ---------------------------------------------------------------------------
// ConvLinformerSelfAttention (MI355X/gfx950) — bf16 MFMA pipeline, round 3.
// global_load_lds(16B) staging + 2-phase double-buffer + seg-XOR LDS swizzle.
// ---------------------------------------------------------------------------

typedef short v8s __attribute__((ext_vector_type(8)));   // 8 x bf16 bits
typedef float v4f __attribute__((ext_vector_type(4)));

#define MFMA16(a, b, c) __builtin_amdgcn_mfma_f32_16x16x32_bf16((a), (b), (c), 0, 0, 0)

__device__ __forceinline__ unsigned short f2bf(float f) {
  unsigned int u = __float_as_uint(f);
  u += 0x7fffu + ((u >> 16) & 1u);   // RNE
  return (unsigned short)(u >> 16);
}

__device__ __forceinline__ v8s cvt8(float4 a, float4 b) {
  v8s v;
  v[0] = (short)f2bf(a.x); v[1] = (short)f2bf(a.y);
  v[2] = (short)f2bf(a.z); v[3] = (short)f2bf(a.w);
  v[4] = (short)f2bf(b.x); v[5] = (short)f2bf(b.y);
  v[6] = (short)f2bf(b.z); v[7] = (short)f2bf(b.w);
  return v;
}

// async global->LDS, 16B per lane; LDS dest = uniform base + lane*16.
__device__ __forceinline__ void gld16(void* lds, const void* g) {
  __builtin_amdgcn_global_load_lds(
      (const __attribute__((address_space(1))) void*)g,
      (__attribute__((address_space(3))) void*)lds, 16, 0, 0);
}

// Fragment pointer into a swizzled [rows][32] bf16 LDS tile.
// Storage: LDS(row, seg') holds global seg = seg' ^ ((row>>1)&3).
// Reader wants global seg g -> read seg' = g ^ ((row>>1)&3).
__device__ __forceinline__ const v8s* frag_ptr(const short* base, int row, int g) {
  return (const v8s*)(base + row * 32 + (((g ^ (row >> 1)) & 3) << 3));
}

// --------------------------------------------------------------- cvt f32->bf16
__global__ __launch_bounds__(256) void k_cvt(const float* __restrict__ src,
                                             short* __restrict__ dst, int n8) {
  const int i = blockIdx.x * 256 + threadIdx.x;
  if (i >= n8) return;
  const float4* s = (const float4*)src;
  ((v8s*)dst)[i] = cvt8(s[2 * i], s[2 * i + 1]);
}

// --------------------------------------------------------------- reorder Wpk
// Wpk (k,n,t) f32 -> Wr (t,k,n) bf16.  grid 16384 (k*64 + ntile), 256 thr.
__global__ __launch_bounds__(256) void k_reorder_wpk(const float* __restrict__ Wpk,
                                                     short* __restrict__ Wr) {
  __shared__ short T[64][40];
  const int k  = blockIdx.x >> 6;
  const int n0 = (blockIdx.x & 63) << 6;
  const int tid = threadIdx.x;
  {
    const int i = tid >> 2, t0 = (tid & 3) << 3;
    const float* p = Wpk + ((size_t)k * 4096 + n0 + i) * 32 + t0;
    float4 a = *(const float4*)p, b = *(const float4*)(p + 4);
    *(v8s*)&T[i][t0] = cvt8(a, b);
  }
  __syncthreads();
  {
    const int t = tid >> 3, j0 = (tid & 7) << 3;
    v8s o;
#pragma unroll
    for (int q = 0; q < 8; ++q) o[q] = T[j0 + q][t];
    *(v8s*)(Wr + ((size_t)t * 256 + k) * 4096 + n0 + j0) = o;
  }
}

// --------------------------------------------------------------- init Kc
__global__ __launch_bounds__(256) void k_init_kc(const float* __restrict__ bpk,
                                                 float* __restrict__ Kc) {
  const int idx = (blockIdx.x * 256 + threadIdx.x) * 4;
  const float v = bpk[(idx >> 10) & 255];
  float4 f; f.x = v; f.y = v; f.z = v; f.w = v;
  *(float4*)(Kc + idx) = f;
}

// --------------------------------------------------------------- zero pads
// KpTp rows 0..14 and 1039..1055 per batch = zeros. grid 256, 256 thr.
__global__ __launch_bounds__(256) void k_zero_pad(short* __restrict__ KpTp) {
  const int idx = blockIdx.x * 256 + threadIdx.x;   // < 65536
  const int ridx = idx >> 9, col8 = idx & 511;
  const int b = ridx >> 5, rr = ridx & 31;
  const int row = (rr < 15) ? rr : 1039 + (rr - 15);
  v8s z = {0, 0, 0, 0, 0, 0, 0, 0};
  *(v8s*)(KpTp + ((size_t)b * 1056 + row) * 4096 + col8 * 8) = z;
}

// --------------------------------------------------------------- QK GEMM v2
// [Q|Kp](16384x2048) = xbf @ Wqk^T.  grid (128,16), 256 thr, 2-phase gload_lds.
__global__ __launch_bounds__(256) void k_gemm_qk_v2(const short* __restrict__ xbf,
                                                    const short* __restrict__ Wqk,
                                                    short* __restrict__ Qbf,
                                                    short* __restrict__ Kp) {
  __shared__ short As[2][128][32];
  __shared__ short Bs[2][128][32];
  const int tid = threadIdx.x, lane = tid & 63, w = tid >> 6;
  const int m0 = blockIdx.x * 128, j0 = blockIdx.y * 128;
  const int wr = (w >> 1) * 64, wc = (w & 1) * 64;
  const int l15 = lane & 15, g = lane >> 4;
  const int sr = lane >> 2, sseg = lane & 3;

  v4f acc[4][4];
#pragma unroll
  for (int i = 0; i < 4; ++i)
#pragma unroll
    for (int j = 0; j < 4; ++j) acc[i][j] = (v4f)0.0f;

  auto stage = [&](int buf, int k0) {
#pragma unroll
    for (int q0 = 0; q0 < 2; ++q0) {
      const int rblk = (w * 2 + q0) << 4, r = rblk + sr;
      const int co = ((sseg ^ (r >> 1)) & 3) << 3;
      gld16(&As[buf][rblk][0], xbf + (size_t)(m0 + r) * 1024 + k0 + co);
      gld16(&Bs[buf][rblk][0], Wqk + (size_t)(j0 + r) * 1024 + k0 + co);
    }
  };

  stage(0, 0);
  __syncthreads();
#pragma unroll 1
  for (int k0 = 0, buf = 0; k0 < 1024; k0 += 32, buf ^= 1) {
    if (k0 + 32 < 1024) stage(buf ^ 1, k0 + 32);
    v8s af[4], bf4[4];
#pragma unroll
    for (int mi = 0; mi < 4; ++mi)
      af[mi] = *frag_ptr(&As[buf][0][0], wr + mi * 16 + l15, g);
#pragma unroll
    for (int ni = 0; ni < 4; ++ni)
      bf4[ni] = *frag_ptr(&Bs[buf][0][0], wc + ni * 16 + l15, g);
#pragma unroll
    for (int ni = 0; ni < 4; ++ni)
#pragma unroll
      for (int mi = 0; mi < 4; ++mi)
        acc[mi][ni] = MFMA16(af[mi], bf4[ni], acc[mi][ni]);
    __syncthreads();
  }
  const int rbase = (lane >> 4) * 4;
#pragma unroll
  for (int mi = 0; mi < 4; ++mi)
#pragma unroll
    for (int ni = 0; ni < 4; ++ni) {
      const int col = j0 + wc + ni * 16 + l15;
      short* dst = (col < 1024) ? Qbf : Kp;
      const int cj = (col < 1024) ? col : col - 1024;
#pragma unroll
      for (int r = 0; r < 4; ++r) {
        const int row = m0 + wr + mi * 16 + rbase + r;
        dst[(size_t)row * 1024 + cj] = (short)f2bf(acc[mi][ni][r]);
      }
    }
}

// --------------------------------------------------------------- transpose+pad
// Kp(4,4096,1024) -> KpTp(4,1056,4096) at row offset 15. grid (64,16,4).
__global__ __launch_bounds__(256) void k_transpose_pad(const short* __restrict__ src,
                                                       short* __restrict__ dst) {
  __shared__ short T[64][72];
  const int r0 = blockIdx.x * 64, c0 = blockIdx.y * 64, b = blockIdx.z;
  const int tid = threadIdx.x;
  {
    const int i = tid >> 2, q = (tid & 3) << 4;
    const short* ps = src + ((size_t)b * 4096 + r0 + i) * 1024 + c0 + q;
    *(v8s*)&T[i][q]     = *(const v8s*)ps;
    *(v8s*)&T[i][q + 8] = *(const v8s*)(ps + 8);
  }
  __syncthreads();
  {
    const int j = tid >> 2, p = (tid & 3) << 4;
    v8s o0, o1;
#pragma unroll
    for (int t = 0; t < 8; ++t) o0[t] = T[p + t][j];
#pragma unroll
    for (int t = 0; t < 8; ++t) o1[t] = T[p + 8 + t][j];
    short* pd = dst + ((size_t)b * 1056 + 15 + c0 + j) * 4096 + r0 + p;
    *(v8s*)pd = o0;
    *(v8s*)(pd + 8) = o1;
  }
}

// --------------------------------------------------------------- conv GEMM v2
// Kc[b][k][d] += sum_t Wr[t] @ shifted(KpTp).  grid 512, 2-phase pipeline.
__global__ __launch_bounds__(256) void k_conv_v2(const short* __restrict__ Wr,
                                                 const short* __restrict__ KpTp,
                                                 float* __restrict__ Kc) {
  __shared__ short As[2][2][128][32];   // dbuf x 2 t-planes
  __shared__ short Kt[2][160][32];      // dbuf halo'd KpTp slice
  // XCD-grouped decode: 32 blocks sharing one Wr (mt,ns) slice -> same XCD.
  const int L = blockIdx.x;
  const int xcd = L & 7, jj = L >> 3;
  const int slice = xcd + ((jj >> 5) << 3), win = jj & 31;
  const int mt = slice >> 3, ns = slice & 7, nt = win >> 2, b = win & 3;
  const int K0 = mt * 128, D0 = nt * 128;
  const int tid = threadIdx.x, lane = tid & 63, w = tid >> 6;
  const int wr = (w >> 1) * 64, wc = (w & 1) * 64;
  const int l15 = lane & 15, g = lane >> 4;
  const int sr = lane >> 2, sseg = lane & 3;
  const short* KpTb = KpTp + (size_t)b * 1056 * 4096;

  v4f acc[4][4];
#pragma unroll
  for (int i = 0; i < 4; ++i)
#pragma unroll
    for (int j = 0; j < 4; ++j) acc[i][j] = (v4f)0.0f;

  auto stageAs = [&](int buf, int nc, int tp) {
    const int n0 = ns * 512 + nc * 32, t0 = tp * 2;
#pragma unroll
    for (int q0 = 0; q0 < 4; ++q0) {
      const int q = w + q0 * 4;                    // 16 loads over 4 waves
      const int pl = q >> 3, rblk = (q & 7) << 4, r = rblk + sr;
      gld16(&As[buf][pl][rblk][0],
            Wr + ((size_t)(t0 + pl) * 256 + K0 + r) * 4096 + n0 +
                (((sseg ^ (r >> 1)) & 3) << 3));
    }
  };
  auto stageKt = [&](int buf, int nc) {
    const int n0 = ns * 512 + nc * 32;
    for (int q = w; q < 10; q += 4) {              // 10 loads over 4 waves
      const int rblk = q << 4, r = rblk + sr;
      gld16(&Kt[buf][rblk][0],
            KpTb + (size_t)(D0 + r) * 4096 + n0 + (((sseg ^ (r >> 1)) & 3) << 3));
    }
  };

  stageKt(0, 0);
  stageAs(0, 0, 0);
  __syncthreads();
  int ab = 0, kb = 0;
#pragma unroll 1
  for (int ph = 0; ph < 256; ++ph) {               // 16 nc x 16 t-pair phases
    const int tp = ph & 15;
    if (ph < 255) {
      const int nn = (ph + 1) >> 4, np = (ph + 1) & 15;
      stageAs(ab ^ 1, nn, np);
      if (np == 0) stageKt(kb ^ 1, nn);
    }
#pragma unroll
    for (int pl = 0; pl < 2; ++pl) {
      const int t = tp * 2 + pl;
      v8s af[4], bf4[4];
#pragma unroll
      for (int mi = 0; mi < 4; ++mi)
        af[mi] = *frag_ptr(&As[ab][pl][0][0], wr + mi * 16 + l15, g);
#pragma unroll
      for (int ni = 0; ni < 4; ++ni)
        bf4[ni] = *frag_ptr(&Kt[kb][0][0], wc + ni * 16 + l15 + t, g);
#pragma unroll
      for (int ni = 0; ni < 4; ++ni)
#pragma unroll
        for (int mi = 0; mi < 4; ++mi)
          acc[mi][ni] = MFMA16(af[mi], bf4[ni], acc[mi][ni]);
    }
    __syncthreads();
    ab ^= 1;
    kb ^= (tp == 15) ? 1 : 0;
  }

  float* kcb = Kc + (size_t)b * 256 * 1024;
  const int rbase = (lane >> 4) * 4;
#pragma unroll
  for (int mi = 0; mi < 4; ++mi)
#pragma unroll
    for (int ni = 0; ni < 4; ++ni)
#pragma unroll
      for (int r = 0; r < 4; ++r)
        atomicAdd(kcb + (size_t)(K0 + wr + mi * 16 + rbase + r) * 1024 +
                      (D0 + wc + ni * 16 + l15),
                  acc[mi][ni][r]);
}

// --------------------------------------------------------------- Kc post
__global__ __launch_bounds__(256) void k_kc_post(const float* __restrict__ Kc,
                                                 short* __restrict__ Kcbf,
                                                 short* __restrict__ KcT) {
  __shared__ short T[64][72];
  const int k0 = blockIdx.x * 64, d0 = blockIdx.y * 64, b = blockIdx.z;
  const int tid = threadIdx.x;
  {
    const int i = tid >> 2, q = (tid & 3) << 4;
    const float* ps = Kc + (size_t)(b * 256 + k0 + i) * 1024 + d0 + q;
    float4 f0 = *(const float4*)ps,       f1 = *(const float4*)(ps + 4);
    float4 f2 = *(const float4*)(ps + 8), f3 = *(const float4*)(ps + 12);
    v8s v0 = cvt8(f0, f1), v1 = cvt8(f2, f3);
    *(v8s*)&T[i][q] = v0;
    *(v8s*)&T[i][q + 8] = v1;
    short* pc = Kcbf + (size_t)(b * 256 + k0 + i) * 1024 + d0 + q;
    *(v8s*)pc = v0;
    *(v8s*)(pc + 8) = v1;
  }
  __syncthreads();
  {
    const int j = tid >> 2, p = (tid & 3) << 4;
    v8s o0, o1;
#pragma unroll
    for (int t = 0; t < 8; ++t) o0[t] = T[p + t][j];
#pragma unroll
    for (int t = 0; t < 8; ++t) o1[t] = T[p + 8 + t][j];
    short* pd = KcT + (size_t)(b * 1024 + d0 + j) * 256 + k0 + p;
    *(v8s*)pd = o0;
    *(v8s*)(pd + 8) = o1;
  }
}

// --------------------------------------------------------------- attention
__global__ __launch_bounds__(256) void k_attn(const short* __restrict__ Qbf,
                                              const short* __restrict__ Kcbf,
                                              const short* __restrict__ KcT,
                                              short* __restrict__ AO) {
  __shared__ short P[4][16][264];
  const int nt = blockIdx.x, h = blockIdx.y, b = blockIdx.z;
  const int tid = threadIdx.x, lane = tid & 63, w = tid >> 6;
  const int l15 = lane & 15, lg4 = (lane >> 4) * 4, lg8 = (lane >> 4) * 8;
  const float scale = 0.08838834764831845f;
  const size_t qb  = (size_t)b * 4096 * 1024 + (size_t)h * 128;
  const size_t kb  = (size_t)b * 256 * 1024 + (size_t)h * 128;
  const size_t vtb = ((size_t)b * 1024 + (size_t)h * 128) * 256;
  short (*Pw)[264] = P[w];
  const int n_wave = nt * 128 + w * 32;

#pragma unroll 1
  for (int half = 0; half < 2; ++half) {
    const int nbase = n_wave + half * 16;
    v8s aq[4];
#pragma unroll
    for (int kt = 0; kt < 4; ++kt)
      aq[kt] = *(const v8s*)(Qbf + qb + (size_t)(nbase + l15) * 1024 + kt * 32 + lg8);

    v4f dacc[16];
#pragma unroll
    for (int ct = 0; ct < 16; ++ct) dacc[ct] = (v4f)0.0f;
#pragma unroll 1
    for (int kt = 0; kt < 4; ++kt) {
#pragma unroll
      for (int ct = 0; ct < 16; ++ct) {
        v8s bk = *(const v8s*)(Kcbf + kb + (size_t)(ct * 16 + l15) * 1024 + kt * 32 + lg8);
        dacc[ct] = MFMA16(aq[kt], bk, dacc[ct]);
      }
    }
#pragma unroll
    for (int ct = 0; ct < 16; ++ct) dacc[ct] = dacc[ct] * scale;
    v4f m4 = dacc[0];
#pragma unroll
    for (int ct = 1; ct < 16; ++ct)
#pragma unroll
      for (int r = 0; r < 4; ++r) m4[r] = fmaxf(m4[r], dacc[ct][r]);
#pragma unroll
    for (int off = 1; off < 16; off <<= 1)
#pragma unroll
      for (int r = 0; r < 4; ++r) m4[r] = fmaxf(m4[r], __shfl_xor(m4[r], off, 64));
    v4f ssum = (v4f)0.0f;
#pragma unroll
    for (int ct = 0; ct < 16; ++ct)
#pragma unroll
      for (int r = 0; r < 4; ++r) {
        const float e = __expf(dacc[ct][r] - m4[r]);
        ssum[r] += e;
        Pw[lg4 + r][ct * 16 + l15] = (short)f2bf(e);
      }
#pragma unroll
    for (int off = 1; off < 16; off <<= 1)
#pragma unroll
      for (int r = 0; r < 4; ++r) ssum[r] += __shfl_xor(ssum[r], off, 64);
    __syncthreads();

    v4f oacc[8];
#pragma unroll
    for (int ct = 0; ct < 8; ++ct) oacc[ct] = (v4f)0.0f;
#pragma unroll 1
    for (int kt2 = 0; kt2 < 8; ++kt2) {
      v8s pa = *(const v8s*)&Pw[l15][kt2 * 32 + lg8];
#pragma unroll
      for (int ct = 0; ct < 8; ++ct) {
        v8s bv = *(const v8s*)(KcT + vtb + (size_t)(ct * 16 + l15) * 256 + kt2 * 32 + lg8);
        oacc[ct] = MFMA16(pa, bv, oacc[ct]);
      }
    }
    v4f inv;
#pragma unroll
    for (int r = 0; r < 4; ++r) inv[r] = 1.0f / ssum[r];
#pragma unroll
    for (int ct = 0; ct < 8; ++ct)
#pragma unroll
      for (int r = 0; r < 4; ++r)
        AO[qb + (size_t)(nbase + lg4 + r) * 1024 + ct * 16 + l15] =
            (short)f2bf(oacc[ct][r] * inv[r]);
    __syncthreads();
  }
}

// --------------------------------------------------------------- out GEMM v2
// out(16384x1024) f32 = AO @ Wobf^T + bo. grid (128,8), 2-phase gload_lds.
__global__ __launch_bounds__(256) void k_gemm_out_v2(const short* __restrict__ AO,
                                                     const short* __restrict__ Wobf,
                                                     const float* __restrict__ bo,
                                                     float* __restrict__ out) {
  __shared__ short As[2][128][32];
  __shared__ short Bs[2][128][32];
  const int tid = threadIdx.x, lane = tid & 63, w = tid >> 6;
  const int m0 = blockIdx.x * 128, j0 = blockIdx.y * 128;
  const int wr = (w >> 1) * 64, wc = (w & 1) * 64;
  const int l15 = lane & 15, g = lane >> 4;
  const int sr = lane >> 2, sseg = lane & 3;

  v4f acc[4][4];
#pragma unroll
  for (int i = 0; i < 4; ++i)
#pragma unroll
    for (int j = 0; j < 4; ++j) acc[i][j] = (v4f)0.0f;

  auto stage = [&](int buf, int k0) {
#pragma unroll
    for (int q0 = 0; q0 < 2; ++q0) {
      const int rblk = (w * 2 + q0) << 4, r = rblk + sr;
      const int co = ((sseg ^ (r >> 1)) & 3) << 3;
      gld16(&As[buf][rblk][0], AO + (size_t)(m0 + r) * 1024 + k0 + co);
      gld16(&Bs[buf][rblk][0], Wobf + (size_t)(j0 + r) * 1024 + k0 + co);
    }
  };

  stage(0, 0);
  __syncthreads();
#pragma unroll 1
  for (int k0 = 0, buf = 0; k0 < 1024; k0 += 32, buf ^= 1) {
    if (k0 + 32 < 1024) stage(buf ^ 1, k0 + 32);
    v8s af[4], bf4[4];
#pragma unroll
    for (int mi = 0; mi < 4; ++mi)
      af[mi] = *frag_ptr(&As[buf][0][0], wr + mi * 16 + l15, g);
#pragma unroll
    for (int ni = 0; ni < 4; ++ni)
      bf4[ni] = *frag_ptr(&Bs[buf][0][0], wc + ni * 16 + l15, g);
#pragma unroll
    for (int ni = 0; ni < 4; ++ni)
#pragma unroll
      for (int mi = 0; mi < 4; ++mi)
        acc[mi][ni] = MFMA16(af[mi], bf4[ni], acc[mi][ni]);
    __syncthreads();
  }
  const int rbase = (lane >> 4) * 4;
#pragma unroll
  for (int mi = 0; mi < 4; ++mi)
#pragma unroll
    for (int ni = 0; ni < 4; ++ni) {
      const int col = j0 + wc + ni * 16 + l15;
      const float bias = bo[col];
#pragma unroll
      for (int r = 0; r < 4; ++r) {
        const int row = m0 + wr + mi * 16 + rbase + r;
        out[(size_t)row * 1024 + col] = acc[mi][ni][r] + bias;
      }
    }
}

// ---------------------------------------------------------------------------
extern "C" void kernel_launch(void* const* d_in, const int* in_sizes, int n_in,
                              void* d_out, int out_size, void* d_ws, size_t ws_size,
                              hipStream_t stream) {
  const float* x   = (const float*)d_in[0];
  const float* Wq  = (const float*)d_in[1];
  const float* Wk  = (const float*)d_in[2];
  const float* Wpk = (const float*)d_in[3];
  const float* bpk = (const float*)d_in[4];
  const float* Wo  = (const float*)d_in[5];
  const float* bo  = (const float*)d_in[6];

  // workspace layout (bytes) — aliased; NEED kept at round-2-verified value.
  const size_t OFF_WR   = 0;            // Wr   (32,256,4096) bf16   67,108,864
  const size_t OFF_XBF  = 67108864;     // xbf  (16384,1024)  bf16   33,554,432
  const size_t OFF_WQK  = 100663296;    // Wqk  (2048,1024)   bf16    4,194,304
  const size_t OFF_KPTP = 67108864;     // KpTp (4,1056,4096) bf16   34,603,008 (aliases xbf+Wqk head)
  const size_t OFF_KCBF = 67108864;     // Kcbf (4,256,1024)  bf16    2,097,152 (after conv)
  const size_t OFF_KCT  = 69206016;     // KcT  (4,1024,256)  bf16    2,097,152
  const size_t OFF_WOBF = 101711872;    // Wobf (1024,1024)   bf16    2,097,152 (after transpose)
  const size_t OFF_QBF  = 104857600;    // Qbf  (4,4096,1024) bf16   33,554,432
  const size_t OFF_KP   = 138412032;    // Kp/AO(4,4096,1024) bf16   33,554,432
  const size_t OFF_KC   = 171966464;    // Kc   (4,256,1024)  f32     4,194,304
  const size_t NEED     = 176160768;
  if (ws_size < NEED) return;

  char* ws = (char*)d_ws;
  short* Wr   = (short*)(ws + OFF_WR);
  short* xbf  = (short*)(ws + OFF_XBF);
  short* Wqk  = (short*)(ws + OFF_WQK);
  short* KpTp = (short*)(ws + OFF_KPTP);
  short* Kcbf = (short*)(ws + OFF_KCBF);
  short* KcT  = (short*)(ws + OFF_KCT);
  short* Wobf = (short*)(ws + OFF_WOBF);
  short* Qbf  = (short*)(ws + OFF_QBF);
  short* Kp   = (short*)(ws + OFF_KP);
  float* Kc   = (float*)(ws + OFF_KC);
  short* AO   = Kp;
  float* outp = (float*)d_out;

  k_cvt<<<dim3(8192), dim3(256), 0, stream>>>(x, xbf, 16777216 / 8);
  k_cvt<<<dim3(512),  dim3(256), 0, stream>>>(Wq, Wqk, 1048576 / 8);
  k_cvt<<<dim3(512),  dim3(256), 0, stream>>>(Wk, Wqk + 1048576, 1048576 / 8);
  k_reorder_wpk<<<dim3(16384), dim3(256), 0, stream>>>(Wpk, Wr);
  k_init_kc<<<dim3(1024), dim3(256), 0, stream>>>(bpk, Kc);
  k_gemm_qk_v2<<<dim3(128, 16), dim3(256), 0, stream>>>(xbf, Wqk, Qbf, Kp);
  k_transpose_pad<<<dim3(64, 16, 4), dim3(256), 0, stream>>>(Kp, KpTp);
  k_cvt<<<dim3(512), dim3(256), 0, stream>>>(Wo, Wobf, 1048576 / 8);
  k_zero_pad<<<dim3(256), dim3(256), 0, stream>>>(KpTp);
  k_conv_v2<<<dim3(512), dim3(256), 0, stream>>>(Wr, KpTp, Kc);
  k_kc_post<<<dim3(4, 16, 4), dim3(256), 0, stream>>>(Kc, Kcbf, KcT);
  k_attn<<<dim3(32, 8, 4), dim3(256), 0, stream>>>(Qbf, Kcbf, KcT, AO);
  k_gemm_out_v2<<<dim3(128, 8), dim3(256), 0, stream>>>(AO, Wobf, bo, outp);
}

// Round 4
// 638.375 us; speedup vs baseline: 1.1608x; 1.0086x over previous
//
#include <hip/hip_runtime.h>

// ---------------------------------------------------------------------------
// ConvLinformerSelfAttention (MI355X/gfx950) — bf16 MFMA pipeline, round 4.
// T4: counted s_waitcnt vmcnt(N) + raw s_barrier (no drain-0 at barriers).
// conv: depth-2 prefetch (triple-buffered As). GEMMs: depth-1 counted.
// ---------------------------------------------------------------------------

typedef short v8s __attribute__((ext_vector_type(8)));   // 8 x bf16 bits
typedef float v4f __attribute__((ext_vector_type(4)));

#define MFMA16(a, b, c) __builtin_amdgcn_mfma_f32_16x16x32_bf16((a), (b), (c), 0, 0, 0)
#define WAITV(N) asm volatile("s_waitcnt vmcnt(" #N ")" ::: "memory")
#define SBAR() __builtin_amdgcn_s_barrier()

__device__ __forceinline__ unsigned short f2bf(float f) {
  unsigned int u = __float_as_uint(f);
  u += 0x7fffu + ((u >> 16) & 1u);   // RNE
  return (unsigned short)(u >> 16);
}

__device__ __forceinline__ v8s cvt8(float4 a, float4 b) {
  v8s v;
  v[0] = (short)f2bf(a.x); v[1] = (short)f2bf(a.y);
  v[2] = (short)f2bf(a.z); v[3] = (short)f2bf(a.w);
  v[4] = (short)f2bf(b.x); v[5] = (short)f2bf(b.y);
  v[6] = (short)f2bf(b.z); v[7] = (short)f2bf(b.w);
  return v;
}

// async global->LDS, 16B per lane; LDS dest = uniform base + lane*16.
__device__ __forceinline__ void gld16(void* lds, const void* g) {
  __builtin_amdgcn_global_load_lds(
      (const __attribute__((address_space(1))) void*)g,
      (__attribute__((address_space(3))) void*)lds, 16, 0, 0);
}

// Fragment pointer into a swizzled [rows][32] bf16 LDS tile.
// Storage: LDS(row, seg') holds global seg = seg' ^ ((row>>1)&3).
__device__ __forceinline__ const v8s* frag_ptr(const short* base, int row, int g) {
  return (const v8s*)(base + row * 32 + (((g ^ (row >> 1)) & 3) << 3));
}

// --------------------------------------------------------------- cvt f32->bf16
__global__ __launch_bounds__(256) void k_cvt(const float* __restrict__ src,
                                             short* __restrict__ dst, int n8) {
  const int i = blockIdx.x * 256 + threadIdx.x;
  if (i >= n8) return;
  const float4* s = (const float4*)src;
  ((v8s*)dst)[i] = cvt8(s[2 * i], s[2 * i + 1]);
}

// --------------------------------------------------------------- reorder Wpk
__global__ __launch_bounds__(256) void k_reorder_wpk(const float* __restrict__ Wpk,
                                                     short* __restrict__ Wr) {
  __shared__ short T[64][40];
  const int k  = blockIdx.x >> 6;
  const int n0 = (blockIdx.x & 63) << 6;
  const int tid = threadIdx.x;
  {
    const int i = tid >> 2, t0 = (tid & 3) << 3;
    const float* p = Wpk + ((size_t)k * 4096 + n0 + i) * 32 + t0;
    float4 a = *(const float4*)p, b = *(const float4*)(p + 4);
    *(v8s*)&T[i][t0] = cvt8(a, b);
  }
  __syncthreads();
  {
    const int t = tid >> 3, j0 = (tid & 7) << 3;
    v8s o;
#pragma unroll
    for (int q = 0; q < 8; ++q) o[q] = T[j0 + q][t];
    *(v8s*)(Wr + ((size_t)t * 256 + k) * 4096 + n0 + j0) = o;
  }
}

// --------------------------------------------------------------- init Kc
__global__ __launch_bounds__(256) void k_init_kc(const float* __restrict__ bpk,
                                                 float* __restrict__ Kc) {
  const int idx = (blockIdx.x * 256 + threadIdx.x) * 4;
  const float v = bpk[(idx >> 10) & 255];
  float4 f; f.x = v; f.y = v; f.z = v; f.w = v;
  *(float4*)(Kc + idx) = f;
}

// --------------------------------------------------------------- zero pads
__global__ __launch_bounds__(256) void k_zero_pad(short* __restrict__ KpTp) {
  const int idx = blockIdx.x * 256 + threadIdx.x;   // < 65536
  const int ridx = idx >> 9, col8 = idx & 511;
  const int b = ridx >> 5, rr = ridx & 31;
  const int row = (rr < 15) ? rr : 1039 + (rr - 15);
  v8s z = {0, 0, 0, 0, 0, 0, 0, 0};
  *(v8s*)(KpTp + ((size_t)b * 1056 + row) * 4096 + col8 * 8) = z;
}

// --------------------------------------------------------------- QK GEMM v3
// [Q|Kp](16384x2048) = xbf @ Wqk^T. grid (128,16). depth-1 counted vmcnt.
__global__ __launch_bounds__(256) void k_gemm_qk_v3(const short* __restrict__ xbf,
                                                    const short* __restrict__ Wqk,
                                                    short* __restrict__ Qbf,
                                                    short* __restrict__ Kp) {
  __shared__ short As[2][128][32];
  __shared__ short Bs[2][128][32];
  const int tid = threadIdx.x, lane = tid & 63, w = tid >> 6;
  const int m0 = blockIdx.x * 128, j0 = blockIdx.y * 128;
  const int wr = (w >> 1) * 64, wc = (w & 1) * 64;
  const int l15 = lane & 15, g = lane >> 4;
  const int sr = lane >> 2, sseg = lane & 3;

  v4f acc[4][4];
#pragma unroll
  for (int i = 0; i < 4; ++i)
#pragma unroll
    for (int j = 0; j < 4; ++j) acc[i][j] = (v4f)0.0f;

  auto stage = [&](int buf, int k0) {
#pragma unroll
    for (int q0 = 0; q0 < 2; ++q0) {
      const int rblk = (w * 2 + q0) << 4, r = rblk + sr;
      const int co = ((sseg ^ (r >> 1)) & 3) << 3;
      gld16(&As[buf][rblk][0], xbf + (size_t)(m0 + r) * 1024 + k0 + co);
      gld16(&Bs[buf][rblk][0], Wqk + (size_t)(j0 + r) * 1024 + k0 + co);
    }
  };

  stage(0, 0);
#pragma unroll 1
  for (int p = 0, buf = 0; p < 32; ++p, buf ^= 1) {
    if (p + 1 < 32) stage(buf ^ 1, (p + 1) * 32);
    if (p < 31) { WAITV(4); } else { WAITV(0); }
    SBAR();
    v8s af[4], bf4[4];
#pragma unroll
    for (int mi = 0; mi < 4; ++mi)
      af[mi] = *frag_ptr(&As[buf][0][0], wr + mi * 16 + l15, g);
#pragma unroll
    for (int ni = 0; ni < 4; ++ni)
      bf4[ni] = *frag_ptr(&Bs[buf][0][0], wc + ni * 16 + l15, g);
#pragma unroll
    for (int ni = 0; ni < 4; ++ni)
#pragma unroll
      for (int mi = 0; mi < 4; ++mi)
        acc[mi][ni] = MFMA16(af[mi], bf4[ni], acc[mi][ni]);
    SBAR();
  }
  const int rbase = (lane >> 4) * 4;
#pragma unroll
  for (int mi = 0; mi < 4; ++mi)
#pragma unroll
    for (int ni = 0; ni < 4; ++ni) {
      const int col = j0 + wc + ni * 16 + l15;
      short* dst = (col < 1024) ? Qbf : Kp;
      const int cj = (col < 1024) ? col : col - 1024;
#pragma unroll
      for (int r = 0; r < 4; ++r) {
        const int row = m0 + wr + mi * 16 + rbase + r;
        dst[(size_t)row * 1024 + cj] = (short)f2bf(acc[mi][ni][r]);
      }
    }
}

// --------------------------------------------------------------- transpose+pad
__global__ __launch_bounds__(256) void k_transpose_pad(const short* __restrict__ src,
                                                       short* __restrict__ dst) {
  __shared__ short T[64][72];
  const int r0 = blockIdx.x * 64, c0 = blockIdx.y * 64, b = blockIdx.z;
  const int tid = threadIdx.x;
  {
    const int i = tid >> 2, q = (tid & 3) << 4;
    const short* ps = src + ((size_t)b * 4096 + r0 + i) * 1024 + c0 + q;
    *(v8s*)&T[i][q]     = *(const v8s*)ps;
    *(v8s*)&T[i][q + 8] = *(const v8s*)(ps + 8);
  }
  __syncthreads();
  {
    const int j = tid >> 2, p = (tid & 3) << 4;
    v8s o0, o1;
#pragma unroll
    for (int t = 0; t < 8; ++t) o0[t] = T[p + t][j];
#pragma unroll
    for (int t = 0; t < 8; ++t) o1[t] = T[p + 8 + t][j];
    short* pd = dst + ((size_t)b * 1056 + 15 + c0 + j) * 4096 + r0 + p;
    *(v8s*)pd = o0;
    *(v8s*)(pd + 8) = o1;
  }
}

// --------------------------------------------------------------- conv GEMM v3
// Kc[b][k][d] += sum_t Wr[t] @ shifted(KpTp). grid 512.
// depth-2 prefetch: As triple-buffered, Kt double-buffered, counted vmcnt.
__global__ __launch_bounds__(256) void k_conv_v3(const short* __restrict__ Wr,
                                                 const short* __restrict__ KpTp,
                                                 float* __restrict__ Kc) {
  __shared__ short As[3][2][128][32];   // 3-deep dbuf x 2 t-planes  (48KB)
  __shared__ short Kt[2][160][32];      // dbuf halo'd KpTp slice    (20KB)
  const int L = blockIdx.x;
  const int xcd = L & 7, jj = L >> 3;
  const int slice = xcd + ((jj >> 5) << 3), win = jj & 31;
  const int mt = slice >> 3, ns = slice & 7, nt = win >> 2, b = win & 3;
  const int K0 = mt * 128, D0 = nt * 128;
  const int tid = threadIdx.x, lane = tid & 63, w = tid >> 6;
  const int wr = (w >> 1) * 64, wc = (w & 1) * 64;
  const int l15 = lane & 15, g = lane >> 4;
  const int sr = lane >> 2, sseg = lane & 3;
  const short* KpTb = KpTp + (size_t)b * 1056 * 4096;

  v4f acc[4][4];
#pragma unroll
  for (int i = 0; i < 4; ++i)
#pragma unroll
    for (int j = 0; j < 4; ++j) acc[i][j] = (v4f)0.0f;

  // ph encodes (nc = ph>>4, tp = ph&15); per wave: 4 gld16.
  auto stageAs = [&](int buf, int ph) {
    const int n0 = ns * 512 + (ph >> 4) * 32, t0 = (ph & 15) * 2;
#pragma unroll
    for (int q0 = 0; q0 < 4; ++q0) {
      const int q = w + q0 * 4;                    // 16 loads over 4 waves
      const int pl = q >> 3, rblk = (q & 7) << 4, r = rblk + sr;
      gld16(&As[buf][pl][rblk][0],
            Wr + ((size_t)(t0 + pl) * 256 + K0 + r) * 4096 + n0 +
                (((sseg ^ (r >> 1)) & 3) << 3));
    }
  };
  // per wave: 2-3 gld16.
  auto stageKt = [&](int buf, int nc) {
    const int n0 = ns * 512 + nc * 32;
    for (int q = w; q < 10; q += 4) {              // 10 loads over 4 waves
      const int rblk = q << 4, r = rblk + sr;
      gld16(&Kt[buf][rblk][0],
            KpTb + (size_t)(D0 + r) * 4096 + n0 + (((sseg ^ (r >> 1)) & 3) << 3));
    }
  };

  stageKt(0, 0);
  stageAs(0, 0);
  stageAs(1, 1);
  int kb = 0;
#pragma unroll 1
  for (int p = 0; p < 256; ++p) {
    const int tp = p & 15;
    if (p + 2 < 256) {
      stageAs((p + 2) % 3, p + 2);
      if (tp == 14) stageKt(kb ^ 1, (p + 2) >> 4);
    }
    // in-order vmcnt retirement: <=8 outstanding  =>  batch(p-2) + older Kt done.
    if (p < 254) { WAITV(8); } else if (p == 254) { WAITV(4); } else { WAITV(0); }
    SBAR();
    const short* Ab = &As[p % 3][0][0][0];
#pragma unroll
    for (int pl = 0; pl < 2; ++pl) {
      const int t = tp * 2 + pl;
      v8s af[4], bf4[4];
#pragma unroll
      for (int mi = 0; mi < 4; ++mi)
        af[mi] = *frag_ptr(Ab + pl * 128 * 32, wr + mi * 16 + l15, g);
#pragma unroll
      for (int ni = 0; ni < 4; ++ni)
        bf4[ni] = *frag_ptr(&Kt[kb][0][0], wc + ni * 16 + l15 + t, g);
#pragma unroll
      for (int ni = 0; ni < 4; ++ni)
#pragma unroll
        for (int mi = 0; mi < 4; ++mi)
          acc[mi][ni] = MFMA16(af[mi], bf4[ni], acc[mi][ni]);
    }
    SBAR();
    if (tp == 15) kb ^= 1;
  }

  float* kcb = Kc + (size_t)b * 256 * 1024;
  const int rbase = (lane >> 4) * 4;
#pragma unroll
  for (int mi = 0; mi < 4; ++mi)
#pragma unroll
    for (int ni = 0; ni < 4; ++ni)
#pragma unroll
      for (int r = 0; r < 4; ++r)
        atomicAdd(kcb + (size_t)(K0 + wr + mi * 16 + rbase + r) * 1024 +
                      (D0 + wc + ni * 16 + l15),
                  acc[mi][ni][r]);
}

// --------------------------------------------------------------- Kc post
__global__ __launch_bounds__(256) void k_kc_post(const float* __restrict__ Kc,
                                                 short* __restrict__ Kcbf,
                                                 short* __restrict__ KcT) {
  __shared__ short T[64][72];
  const int k0 = blockIdx.x * 64, d0 = blockIdx.y * 64, b = blockIdx.z;
  const int tid = threadIdx.x;
  {
    const int i = tid >> 2, q = (tid & 3) << 4;
    const float* ps = Kc + (size_t)(b * 256 + k0 + i) * 1024 + d0 + q;
    float4 f0 = *(const float4*)ps,       f1 = *(const float4*)(ps + 4);
    float4 f2 = *(const float4*)(ps + 8), f3 = *(const float4*)(ps + 12);
    v8s v0 = cvt8(f0, f1), v1 = cvt8(f2, f3);
    *(v8s*)&T[i][q] = v0;
    *(v8s*)&T[i][q + 8] = v1;
    short* pc = Kcbf + (size_t)(b * 256 + k0 + i) * 1024 + d0 + q;
    *(v8s*)pc = v0;
    *(v8s*)(pc + 8) = v1;
  }
  __syncthreads();
  {
    const int j = tid >> 2, p = (tid & 3) << 4;
    v8s o0, o1;
#pragma unroll
    for (int t = 0; t < 8; ++t) o0[t] = T[p + t][j];
#pragma unroll
    for (int t = 0; t < 8; ++t) o1[t] = T[p + 8 + t][j];
    short* pd = KcT + (size_t)(b * 1024 + d0 + j) * 256 + k0 + p;
    *(v8s*)pd = o0;
    *(v8s*)(pd + 8) = o1;
  }
}

// --------------------------------------------------------------- attention
__global__ __launch_bounds__(256) void k_attn(const short* __restrict__ Qbf,
                                              const short* __restrict__ Kcbf,
                                              const short* __restrict__ KcT,
                                              short* __restrict__ AO) {
  __shared__ short P[4][16][264];
  const int nt = blockIdx.x, h = blockIdx.y, b = blockIdx.z;
  const int tid = threadIdx.x, lane = tid & 63, w = tid >> 6;
  const int l15 = lane & 15, lg4 = (lane >> 4) * 4, lg8 = (lane >> 4) * 8;
  const float scale = 0.08838834764831845f;
  const size_t qb  = (size_t)b * 4096 * 1024 + (size_t)h * 128;
  const size_t kb  = (size_t)b * 256 * 1024 + (size_t)h * 128;
  const size_t vtb = ((size_t)b * 1024 + (size_t)h * 128) * 256;
  short (*Pw)[264] = P[w];
  const int n_wave = nt * 128 + w * 32;

#pragma unroll 1
  for (int half = 0; half < 2; ++half) {
    const int nbase = n_wave + half * 16;
    v8s aq[4];
#pragma unroll
    for (int kt = 0; kt < 4; ++kt)
      aq[kt] = *(const v8s*)(Qbf + qb + (size_t)(nbase + l15) * 1024 + kt * 32 + lg8);

    v4f dacc[16];
#pragma unroll
    for (int ct = 0; ct < 16; ++ct) dacc[ct] = (v4f)0.0f;
#pragma unroll 1
    for (int kt = 0; kt < 4; ++kt) {
#pragma unroll
      for (int ct = 0; ct < 16; ++ct) {
        v8s bk = *(const v8s*)(Kcbf + kb + (size_t)(ct * 16 + l15) * 1024 + kt * 32 + lg8);
        dacc[ct] = MFMA16(aq[kt], bk, dacc[ct]);
      }
    }
#pragma unroll
    for (int ct = 0; ct < 16; ++ct) dacc[ct] = dacc[ct] * scale;
    v4f m4 = dacc[0];
#pragma unroll
    for (int ct = 1; ct < 16; ++ct)
#pragma unroll
      for (int r = 0; r < 4; ++r) m4[r] = fmaxf(m4[r], dacc[ct][r]);
#pragma unroll
    for (int off = 1; off < 16; off <<= 1)
#pragma unroll
      for (int r = 0; r < 4; ++r) m4[r] = fmaxf(m4[r], __shfl_xor(m4[r], off, 64));
    v4f ssum = (v4f)0.0f;
#pragma unroll
    for (int ct = 0; ct < 16; ++ct)
#pragma unroll
      for (int r = 0; r < 4; ++r) {
        const float e = __expf(dacc[ct][r] - m4[r]);
        ssum[r] += e;
        Pw[lg4 + r][ct * 16 + l15] = (short)f2bf(e);
      }
#pragma unroll
    for (int off = 1; off < 16; off <<= 1)
#pragma unroll
      for (int r = 0; r < 4; ++r) ssum[r] += __shfl_xor(ssum[r], off, 64);
    __syncthreads();

    v4f oacc[8];
#pragma unroll
    for (int ct = 0; ct < 8; ++ct) oacc[ct] = (v4f)0.0f;
#pragma unroll 1
    for (int kt2 = 0; kt2 < 8; ++kt2) {
      v8s pa = *(const v8s*)&Pw[l15][kt2 * 32 + lg8];
#pragma unroll
      for (int ct = 0; ct < 8; ++ct) {
        v8s bv = *(const v8s*)(KcT + vtb + (size_t)(ct * 16 + l15) * 256 + kt2 * 32 + lg8);
        oacc[ct] = MFMA16(pa, bv, oacc[ct]);
      }
    }
    v4f inv;
#pragma unroll
    for (int r = 0; r < 4; ++r) inv[r] = 1.0f / ssum[r];
#pragma unroll
    for (int ct = 0; ct < 8; ++ct)
#pragma unroll
      for (int r = 0; r < 4; ++r)
        AO[qb + (size_t)(nbase + lg4 + r) * 1024 + ct * 16 + l15] =
            (short)f2bf(oacc[ct][r] * inv[r]);
    __syncthreads();
  }
}

// --------------------------------------------------------------- out GEMM v3
// out(16384x1024) f32 = AO @ Wobf^T + bo. grid (128,8). depth-1 counted vmcnt.
__global__ __launch_bounds__(256) void k_gemm_out_v3(const short* __restrict__ AO,
                                                     const short* __restrict__ Wobf,
                                                     const float* __restrict__ bo,
                                                     float* __restrict__ out) {
  __shared__ short As[2][128][32];
  __shared__ short Bs[2][128][32];
  const int tid = threadIdx.x, lane = tid & 63, w = tid >> 6;
  const int m0 = blockIdx.x * 128, j0 = blockIdx.y * 128;
  const int wr = (w >> 1) * 64, wc = (w & 1) * 64;
  const int l15 = lane & 15, g = lane >> 4;
  const int sr = lane >> 2, sseg = lane & 3;

  v4f acc[4][4];
#pragma unroll
  for (int i = 0; i < 4; ++i)
#pragma unroll
    for (int j = 0; j < 4; ++j) acc[i][j] = (v4f)0.0f;

  auto stage = [&](int buf, int k0) {
#pragma unroll
    for (int q0 = 0; q0 < 2; ++q0) {
      const int rblk = (w * 2 + q0) << 4, r = rblk + sr;
      const int co = ((sseg ^ (r >> 1)) & 3) << 3;
      gld16(&As[buf][rblk][0], AO + (size_t)(m0 + r) * 1024 + k0 + co);
      gld16(&Bs[buf][rblk][0], Wobf + (size_t)(j0 + r) * 1024 + k0 + co);
    }
  };

  stage(0, 0);
#pragma unroll 1
  for (int p = 0, buf = 0; p < 32; ++p, buf ^= 1) {
    if (p + 1 < 32) stage(buf ^ 1, (p + 1) * 32);
    if (p < 31) { WAITV(4); } else { WAITV(0); }
    SBAR();
    v8s af[4], bf4[4];
#pragma unroll
    for (int mi = 0; mi < 4; ++mi)
      af[mi] = *frag_ptr(&As[buf][0][0], wr + mi * 16 + l15, g);
#pragma unroll
    for (int ni = 0; ni < 4; ++ni)
      bf4[ni] = *frag_ptr(&Bs[buf][0][0], wc + ni * 16 + l15, g);
#pragma unroll
    for (int ni = 0; ni < 4; ++ni)
#pragma unroll
      for (int mi = 0; mi < 4; ++mi)
        acc[mi][ni] = MFMA16(af[mi], bf4[ni], acc[mi][ni]);
    SBAR();
  }
  const int rbase = (lane >> 4) * 4;
#pragma unroll
  for (int mi = 0; mi < 4; ++mi)
#pragma unroll
    for (int ni = 0; ni < 4; ++ni) {
      const int col = j0 + wc + ni * 16 + l15;
      const float bias = bo[col];
#pragma unroll
      for (int r = 0; r < 4; ++r) {
        const int row = m0 + wr + mi * 16 + rbase + r;
        out[(size_t)row * 1024 + col] = acc[mi][ni][r] + bias;
      }
    }
}

// ---------------------------------------------------------------------------
extern "C" void kernel_launch(void* const* d_in, const int* in_sizes, int n_in,
                              void* d_out, int out_size, void* d_ws, size_t ws_size,
                              hipStream_t stream) {
  const float* x   = (const float*)d_in[0];
  const float* Wq  = (const float*)d_in[1];
  const float* Wk  = (const float*)d_in[2];
  const float* Wpk = (const float*)d_in[3];
  const float* bpk = (const float*)d_in[4];
  const float* Wo  = (const float*)d_in[5];
  const float* bo  = (const float*)d_in[6];

  // workspace layout (bytes) — identical to round-3-verified layout.
  const size_t OFF_WR   = 0;            // Wr   (32,256,4096) bf16   67,108,864
  const size_t OFF_XBF  = 67108864;     // xbf  (16384,1024)  bf16   33,554,432
  const size_t OFF_WQK  = 100663296;    // Wqk  (2048,1024)   bf16    4,194,304
  const size_t OFF_KPTP = 67108864;     // KpTp (4,1056,4096) bf16   34,603,008
  const size_t OFF_KCBF = 67108864;     // Kcbf (4,256,1024)  bf16    2,097,152
  const size_t OFF_KCT  = 69206016;     // KcT  (4,1024,256)  bf16    2,097,152
  const size_t OFF_WOBF = 101711872;    // Wobf (1024,1024)   bf16    2,097,152
  const size_t OFF_QBF  = 104857600;    // Qbf  (4,4096,1024) bf16   33,554,432
  const size_t OFF_KP   = 138412032;    // Kp/AO(4,4096,1024) bf16   33,554,432
  const size_t OFF_KC   = 171966464;    // Kc   (4,256,1024)  f32     4,194,304
  const size_t NEED     = 176160768;
  if (ws_size < NEED) return;

  char* ws = (char*)d_ws;
  short* Wr   = (short*)(ws + OFF_WR);
  short* xbf  = (short*)(ws + OFF_XBF);
  short* Wqk  = (short*)(ws + OFF_WQK);
  short* KpTp = (short*)(ws + OFF_KPTP);
  short* Kcbf = (short*)(ws + OFF_KCBF);
  short* KcT  = (short*)(ws + OFF_KCT);
  short* Wobf = (short*)(ws + OFF_WOBF);
  short* Qbf  = (short*)(ws + OFF_QBF);
  short* Kp   = (short*)(ws + OFF_KP);
  float* Kc   = (float*)(ws + OFF_KC);
  short* AO   = Kp;
  float* outp = (float*)d_out;

  k_cvt<<<dim3(8192), dim3(256), 0, stream>>>(x, xbf, 16777216 / 8);
  k_cvt<<<dim3(512),  dim3(256), 0, stream>>>(Wq, Wqk, 1048576 / 8);
  k_cvt<<<dim3(512),  dim3(256), 0, stream>>>(Wk, Wqk + 1048576, 1048576 / 8);
  k_reorder_wpk<<<dim3(16384), dim3(256), 0, stream>>>(Wpk, Wr);
  k_init_kc<<<dim3(1024), dim3(256), 0, stream>>>(bpk, Kc);
  k_gemm_qk_v3<<<dim3(128, 16), dim3(256), 0, stream>>>(xbf, Wqk, Qbf, Kp);
  k_transpose_pad<<<dim3(64, 16, 4), dim3(256), 0, stream>>>(Kp, KpTp);
  k_cvt<<<dim3(512), dim3(256), 0, stream>>>(Wo, Wobf, 1048576 / 8);
  k_zero_pad<<<dim3(256), dim3(256), 0, stream>>>(KpTp);
  k_conv_v3<<<dim3(512), dim3(256), 0, stream>>>(Wr, KpTp, Kc);
  k_kc_post<<<dim3(4, 16, 4), dim3(256), 0, stream>>>(Kc, Kcbf, KcT);
  k_attn<<<dim3(32, 8, 4), dim3(256), 0, stream>>>(Qbf, Kcbf, KcT, AO);
  k_gemm_out_v3<<<dim3(128, 8), dim3(256), 0, stream>>>(AO, Wobf, bo, outp);
}

// Round 5
// 633.069 us; speedup vs baseline: 1.1705x; 1.0084x over previous
//
#include <hip/hip_runtime.h>

// ---------------------------------------------------------------------------
// ConvLinformerSelfAttention (MI355X/gfx950) — bf16 MFMA pipeline, round 5.
// conv: 256x256 8-phase-style schedule (T3+T4+T5), 512thr, 1 block/CU,
//       depth-2 gload_lds prefetch, counted vmcnt, setprio; partial-sum
//       stores into d_out scratch + k_reduce_kc (replaces atomics).
// ---------------------------------------------------------------------------

typedef short v8s __attribute__((ext_vector_type(8)));   // 8 x bf16 bits
typedef float v4f __attribute__((ext_vector_type(4)));

#define MFMA16(a, b, c) __builtin_amdgcn_mfma_f32_16x16x32_bf16((a), (b), (c), 0, 0, 0)
#define WAITV(N) asm volatile("s_waitcnt vmcnt(" #N ")" ::: "memory")
#define SBAR() __builtin_amdgcn_s_barrier()

__device__ __forceinline__ unsigned short f2bf(float f) {
  unsigned int u = __float_as_uint(f);
  u += 0x7fffu + ((u >> 16) & 1u);   // RNE
  return (unsigned short)(u >> 16);
}

__device__ __forceinline__ v8s cvt8(float4 a, float4 b) {
  v8s v;
  v[0] = (short)f2bf(a.x); v[1] = (short)f2bf(a.y);
  v[2] = (short)f2bf(a.z); v[3] = (short)f2bf(a.w);
  v[4] = (short)f2bf(b.x); v[5] = (short)f2bf(b.y);
  v[6] = (short)f2bf(b.z); v[7] = (short)f2bf(b.w);
  return v;
}

// async global->LDS, 16B per lane; LDS dest = uniform base + lane*16.
__device__ __forceinline__ void gld16(void* lds, const void* g) {
  __builtin_amdgcn_global_load_lds(
      (const __attribute__((address_space(1))) void*)g,
      (__attribute__((address_space(3))) void*)lds, 16, 0, 0);
}

// Fragment pointer into a swizzled [rows][32] bf16 LDS tile.
// Storage: LDS(row, seg') holds global seg = seg' ^ ((row>>1)&3).
__device__ __forceinline__ const v8s* frag_ptr(const short* base, int row, int g) {
  return (const v8s*)(base + row * 32 + (((g ^ (row >> 1)) & 3) << 3));
}

// --------------------------------------------------------------- cvt f32->bf16
__global__ __launch_bounds__(256) void k_cvt(const float* __restrict__ src,
                                             short* __restrict__ dst, int n8) {
  const int i = blockIdx.x * 256 + threadIdx.x;
  if (i >= n8) return;
  const float4* s = (const float4*)src;
  ((v8s*)dst)[i] = cvt8(s[2 * i], s[2 * i + 1]);
}

// --------------------------------------------------------------- reorder Wpk
__global__ __launch_bounds__(256) void k_reorder_wpk(const float* __restrict__ Wpk,
                                                     short* __restrict__ Wr) {
  __shared__ short T[64][40];
  const int k  = blockIdx.x >> 6;
  const int n0 = (blockIdx.x & 63) << 6;
  const int tid = threadIdx.x;
  {
    const int i = tid >> 2, t0 = (tid & 3) << 3;
    const float* p = Wpk + ((size_t)k * 4096 + n0 + i) * 32 + t0;
    float4 a = *(const float4*)p, b = *(const float4*)(p + 4);
    *(v8s*)&T[i][t0] = cvt8(a, b);
  }
  __syncthreads();
  {
    const int t = tid >> 3, j0 = (tid & 7) << 3;
    v8s o;
#pragma unroll
    for (int q = 0; q < 8; ++q) o[q] = T[j0 + q][t];
    *(v8s*)(Wr + ((size_t)t * 256 + k) * 4096 + n0 + j0) = o;
  }
}

// --------------------------------------------------------------- zero pads
__global__ __launch_bounds__(256) void k_zero_pad(short* __restrict__ KpTp) {
  const int idx = blockIdx.x * 256 + threadIdx.x;   // < 65536
  const int ridx = idx >> 9, col8 = idx & 511;
  const int b = ridx >> 5, rr = ridx & 31;
  const int row = (rr < 15) ? rr : 1039 + (rr - 15);
  v8s z = {0, 0, 0, 0, 0, 0, 0, 0};
  *(v8s*)(KpTp + ((size_t)b * 1056 + row) * 4096 + col8 * 8) = z;
}

// --------------------------------------------------------------- QK GEMM v3
__global__ __launch_bounds__(256) void k_gemm_qk_v3(const short* __restrict__ xbf,
                                                    const short* __restrict__ Wqk,
                                                    short* __restrict__ Qbf,
                                                    short* __restrict__ Kp) {
  __shared__ short As[2][128][32];
  __shared__ short Bs[2][128][32];
  const int tid = threadIdx.x, lane = tid & 63, w = tid >> 6;
  const int m0 = blockIdx.x * 128, j0 = blockIdx.y * 128;
  const int wr = (w >> 1) * 64, wc = (w & 1) * 64;
  const int l15 = lane & 15, g = lane >> 4;
  const int sr = lane >> 2, sseg = lane & 3;

  v4f acc[4][4];
#pragma unroll
  for (int i = 0; i < 4; ++i)
#pragma unroll
    for (int j = 0; j < 4; ++j) acc[i][j] = (v4f)0.0f;

  auto stage = [&](int buf, int k0) {
#pragma unroll
    for (int q0 = 0; q0 < 2; ++q0) {
      const int rblk = (w * 2 + q0) << 4, r = rblk + sr;
      const int co = ((sseg ^ (r >> 1)) & 3) << 3;
      gld16(&As[buf][rblk][0], xbf + (size_t)(m0 + r) * 1024 + k0 + co);
      gld16(&Bs[buf][rblk][0], Wqk + (size_t)(j0 + r) * 1024 + k0 + co);
    }
  };

  stage(0, 0);
#pragma unroll 1
  for (int p = 0, buf = 0; p < 32; ++p, buf ^= 1) {
    if (p + 1 < 32) stage(buf ^ 1, (p + 1) * 32);
    if (p < 31) { WAITV(4); } else { WAITV(0); }
    SBAR();
    v8s af[4], bf4[4];
#pragma unroll
    for (int mi = 0; mi < 4; ++mi)
      af[mi] = *frag_ptr(&As[buf][0][0], wr + mi * 16 + l15, g);
#pragma unroll
    for (int ni = 0; ni < 4; ++ni)
      bf4[ni] = *frag_ptr(&Bs[buf][0][0], wc + ni * 16 + l15, g);
#pragma unroll
    for (int ni = 0; ni < 4; ++ni)
#pragma unroll
      for (int mi = 0; mi < 4; ++mi)
        acc[mi][ni] = MFMA16(af[mi], bf4[ni], acc[mi][ni]);
    SBAR();
  }
  const int rbase = (lane >> 4) * 4;
#pragma unroll
  for (int mi = 0; mi < 4; ++mi)
#pragma unroll
    for (int ni = 0; ni < 4; ++ni) {
      const int col = j0 + wc + ni * 16 + l15;
      short* dst = (col < 1024) ? Qbf : Kp;
      const int cj = (col < 1024) ? col : col - 1024;
#pragma unroll
      for (int r = 0; r < 4; ++r) {
        const int row = m0 + wr + mi * 16 + rbase + r;
        dst[(size_t)row * 1024 + cj] = (short)f2bf(acc[mi][ni][r]);
      }
    }
}

// --------------------------------------------------------------- transpose+pad
__global__ __launch_bounds__(256) void k_transpose_pad(const short* __restrict__ src,
                                                       short* __restrict__ dst) {
  __shared__ short T[64][72];
  const int r0 = blockIdx.x * 64, c0 = blockIdx.y * 64, b = blockIdx.z;
  const int tid = threadIdx.x;
  {
    const int i = tid >> 2, q = (tid & 3) << 4;
    const short* ps = src + ((size_t)b * 4096 + r0 + i) * 1024 + c0 + q;
    *(v8s*)&T[i][q]     = *(const v8s*)ps;
    *(v8s*)&T[i][q + 8] = *(const v8s*)(ps + 8);
  }
  __syncthreads();
  {
    const int j = tid >> 2, p = (tid & 3) << 4;
    v8s o0, o1;
#pragma unroll
    for (int t = 0; t < 8; ++t) o0[t] = T[p + t][j];
#pragma unroll
    for (int t = 0; t < 8; ++t) o1[t] = T[p + 8 + t][j];
    short* pd = dst + ((size_t)b * 1056 + 15 + c0 + j) * 4096 + r0 + p;
    *(v8s*)pd = o0;
    *(v8s*)(pd + 8) = o1;
  }
}

// --------------------------------------------------------------- conv GEMM v4
// P[ns][b][kch 256][d 1024-window 256] = sum_{t,n-window} Wr x shifted(KpTp)
// grid 256 = 16 splits x (4b x 4nt); 512 thr, 8 waves (2M x 4N).
__global__ __launch_bounds__(512, 2) void k_conv_v4(const short* __restrict__ Wr,
                                                    const short* __restrict__ KpTp,
                                                    float* __restrict__ Pq) {
  __shared__ short A[3][256][32];    // 48 KB: t-plane A tiles, triple buffer
  __shared__ short Kt[2][384][32];   // 48 KB: halo'd KpTp (287 used rows), dbuf
  const int bid = blockIdx.x;
  // 16 blocks sharing an A-stream (same ns) share bid%8 -> same XCD L2.
  const int ns = (bid & 7) | (((bid >> 7) & 1) << 3);
  const int j  = (bid >> 3) & 15;
  const int b = j >> 2, nt = j & 3;
  const int D0 = nt * 256;
  const int nbase = ns * 256;
  const int tid = threadIdx.x, lane = tid & 63, w = tid >> 6;
  const int wm = (w >> 2) * 128, wn = (w & 3) * 64;
  const int l15 = lane & 15, g = lane >> 4;
  const int lr = lane >> 2, lseg = lane & 3;
  const short* KpTb = KpTp + (size_t)b * 1056 * 4096;

  v4f acc[8][4];
#pragma unroll
  for (int mi = 0; mi < 8; ++mi)
#pragma unroll
    for (int ni = 0; ni < 4; ++ni) acc[mi][ni] = (v4f)0.0f;

  // stage one 128-row round of the A tile for step s2 (1 gld16 per wave).
  auto stageA = [&](int buf, int s2, int q) {
    const int t2 = s2 & 31, c2 = s2 >> 5;
    const int rblk = q * 128 + w * 16;
    const int row = rblk + lr;
    const int sg = ((lseg ^ (row >> 1)) & 3) << 3;
    gld16(&A[buf][rblk][0],
          Wr + ((size_t)t2 * 256 + row) * 4096 + nbase + c2 * 32 + sg);
  };
  // stage one 128-row round of the Kt tile for chunk c1 (rows >=287 junk).
  auto stageKt = [&](int buf, int c1, int q) {
    const int rblk = q * 128 + w * 16;
    const int row = rblk + lr;
    const int srow = row < 287 ? row : 286;
    const int sg = ((lseg ^ (row >> 1)) & 3) << 3;
    gld16(&Kt[buf][rblk][0],
          KpTb + (size_t)(D0 + srow) * 4096 + nbase + c1 * 32 + sg);
  };

  // prologue: A(0), Kt(0), A(1); drain all but A(1)'s 2 rounds.
  stageA(0, 0, 0); stageA(0, 0, 1);
  stageKt(0, 0, 0); stageKt(0, 0, 1); stageKt(0, 0, 2);
  stageA(1, 1, 0); stageA(1, 1, 1);
  WAITV(2);
  SBAR();

  int ab = 0, pab = 2;  // current A buf = s%3; stage target = (s+2)%3 = (s-1)%3
#pragma unroll 1
  for (int s = 0; s < 256; ++s) {
    const int t = s & 31, c = s >> 5;
    const short* Abp = &A[ab][0][0];
    const short* Ktp = &Kt[c & 1][0][0];
    // ---- phase 1: quadrant mi 0..3 ----
    v8s bq[4], aq[4];
#pragma unroll
    for (int ni = 0; ni < 4; ++ni)
      bq[ni] = *frag_ptr(Ktp, wn + ni * 16 + l15 + t, g);
#pragma unroll
    for (int mi = 0; mi < 4; ++mi)
      aq[mi] = *frag_ptr(Abp, wm + mi * 16 + l15, g);
    if (s + 2 < 256) stageA(pab, s + 2, 0);
    SBAR();
    __builtin_amdgcn_s_setprio(1);
#pragma unroll
    for (int ni = 0; ni < 4; ++ni)
#pragma unroll
      for (int mi = 0; mi < 4; ++mi)
        acc[mi][ni] = MFMA16(aq[mi], bq[ni], acc[mi][ni]);
    __builtin_amdgcn_s_setprio(0);
    SBAR();
    // ---- phase 2: quadrant mi 4..7 ----
    v8s aq2[4];
#pragma unroll
    for (int mi = 0; mi < 4; ++mi)
      aq2[mi] = *frag_ptr(Abp, wm + 64 + mi * 16 + l15, g);
    const bool ktst = ((unsigned)(t - 24) <= 2u) && (c < 7);
    if (s + 2 < 256) stageA(pab, s + 2, 1);
    if (ktst) stageKt((c + 1) & 1, c + 1, t - 24);
    SBAR();
    __builtin_amdgcn_s_setprio(1);
#pragma unroll
    for (int ni = 0; ni < 4; ++ni)
#pragma unroll
      for (int mi = 0; mi < 4; ++mi)
        acc[4 + mi][ni] = MFMA16(aq2[mi], bq[ni], acc[4 + mi][ni]);
    __builtin_amdgcn_s_setprio(0);
    // counted wait: A(s+1) (and all older, incl. Kt) retired; keep
    // step-s issues (A(s+2) 2 rounds + optional Kt round) in flight.
    if (s < 254) {
      if (ktst) { WAITV(3); } else { WAITV(2); }
    } else if (s == 254) {
      WAITV(0);
    }
    SBAR();
    pab = ab; ab = (ab == 2) ? 0 : ab + 1;
  }

  float* Pp = Pq + (size_t)(ns * 4 + b) * 262144;  // [256][1024] window
#pragma unroll
  for (int mi = 0; mi < 8; ++mi)
#pragma unroll
    for (int ni = 0; ni < 4; ++ni) {
      const int col = D0 + wn + ni * 16 + l15;
#pragma unroll
      for (int r = 0; r < 4; ++r)
        Pp[(size_t)(wm + mi * 16 + g * 4 + r) * 1024 + col] = acc[mi][ni][r];
    }
}

// --------------------------------------------------------------- reduce Kc
// Kc[i] = bpk[k] + sum_{ns<16} P[ns][i], i over (4,256,1024). grid 1024x256.
__global__ __launch_bounds__(256) void k_reduce_kc(const float* __restrict__ P,
                                                   const float* __restrict__ bpk,
                                                   float* __restrict__ Kc) {
  const int i = (blockIdx.x * 256 + threadIdx.x) * 4;  // < 4*256*1024
  const float bias = bpk[(i >> 10) & 255];
  float4 s; s.x = bias; s.y = bias; s.z = bias; s.w = bias;
#pragma unroll
  for (int ns = 0; ns < 16; ++ns) {
    float4 v = *(const float4*)(P + (size_t)ns * 1048576 + i);
    s.x += v.x; s.y += v.y; s.z += v.z; s.w += v.w;
  }
  *(float4*)(Kc + i) = s;
}

// --------------------------------------------------------------- Kc post
__global__ __launch_bounds__(256) void k_kc_post(const float* __restrict__ Kc,
                                                 short* __restrict__ Kcbf,
                                                 short* __restrict__ KcT) {
  __shared__ short T[64][72];
  const int k0 = blockIdx.x * 64, d0 = blockIdx.y * 64, b = blockIdx.z;
  const int tid = threadIdx.x;
  {
    const int i = tid >> 2, q = (tid & 3) << 4;
    const float* ps = Kc + (size_t)(b * 256 + k0 + i) * 1024 + d0 + q;
    float4 f0 = *(const float4*)ps,       f1 = *(const float4*)(ps + 4);
    float4 f2 = *(const float4*)(ps + 8), f3 = *(const float4*)(ps + 12);
    v8s v0 = cvt8(f0, f1), v1 = cvt8(f2, f3);
    *(v8s*)&T[i][q] = v0;
    *(v8s*)&T[i][q + 8] = v1;
    short* pc = Kcbf + (size_t)(b * 256 + k0 + i) * 1024 + d0 + q;
    *(v8s*)pc = v0;
    *(v8s*)(pc + 8) = v1;
  }
  __syncthreads();
  {
    const int j = tid >> 2, p = (tid & 3) << 4;
    v8s o0, o1;
#pragma unroll
    for (int t = 0; t < 8; ++t) o0[t] = T[p + t][j];
#pragma unroll
    for (int t = 0; t < 8; ++t) o1[t] = T[p + 8 + t][j];
    short* pd = KcT + (size_t)(b * 1024 + d0 + j) * 256 + k0 + p;
    *(v8s*)pd = o0;
    *(v8s*)(pd + 8) = o1;
  }
}

// --------------------------------------------------------------- attention
__global__ __launch_bounds__(256) void k_attn(const short* __restrict__ Qbf,
                                              const short* __restrict__ Kcbf,
                                              const short* __restrict__ KcT,
                                              short* __restrict__ AO) {
  __shared__ short P[4][16][264];
  const int nt = blockIdx.x, h = blockIdx.y, b = blockIdx.z;
  const int tid = threadIdx.x, lane = tid & 63, w = tid >> 6;
  const int l15 = lane & 15, lg4 = (lane >> 4) * 4, lg8 = (lane >> 4) * 8;
  const float scale = 0.08838834764831845f;
  const size_t qb  = (size_t)b * 4096 * 1024 + (size_t)h * 128;
  const size_t kb  = (size_t)b * 256 * 1024 + (size_t)h * 128;
  const size_t vtb = ((size_t)b * 1024 + (size_t)h * 128) * 256;
  short (*Pw)[264] = P[w];
  const int n_wave = nt * 128 + w * 32;

#pragma unroll 1
  for (int half = 0; half < 2; ++half) {
    const int nbase = n_wave + half * 16;
    v8s aq[4];
#pragma unroll
    for (int kt = 0; kt < 4; ++kt)
      aq[kt] = *(const v8s*)(Qbf + qb + (size_t)(nbase + l15) * 1024 + kt * 32 + lg8);

    v4f dacc[16];
#pragma unroll
    for (int ct = 0; ct < 16; ++ct) dacc[ct] = (v4f)0.0f;
#pragma unroll 1
    for (int kt = 0; kt < 4; ++kt) {
#pragma unroll
      for (int ct = 0; ct < 16; ++ct) {
        v8s bk = *(const v8s*)(Kcbf + kb + (size_t)(ct * 16 + l15) * 1024 + kt * 32 + lg8);
        dacc[ct] = MFMA16(aq[kt], bk, dacc[ct]);
      }
    }
#pragma unroll
    for (int ct = 0; ct < 16; ++ct) dacc[ct] = dacc[ct] * scale;
    v4f m4 = dacc[0];
#pragma unroll
    for (int ct = 1; ct < 16; ++ct)
#pragma unroll
      for (int r = 0; r < 4; ++r) m4[r] = fmaxf(m4[r], dacc[ct][r]);
#pragma unroll
    for (int off = 1; off < 16; off <<= 1)
#pragma unroll
      for (int r = 0; r < 4; ++r) m4[r] = fmaxf(m4[r], __shfl_xor(m4[r], off, 64));
    v4f ssum = (v4f)0.0f;
#pragma unroll
    for (int ct = 0; ct < 16; ++ct)
#pragma unroll
      for (int r = 0; r < 4; ++r) {
        const float e = __expf(dacc[ct][r] - m4[r]);
        ssum[r] += e;
        Pw[lg4 + r][ct * 16 + l15] = (short)f2bf(e);
      }
#pragma unroll
    for (int off = 1; off < 16; off <<= 1)
#pragma unroll
      for (int r = 0; r < 4; ++r) ssum[r] += __shfl_xor(ssum[r], off, 64);
    __syncthreads();

    v4f oacc[8];
#pragma unroll
    for (int ct = 0; ct < 8; ++ct) oacc[ct] = (v4f)0.0f;
#pragma unroll 1
    for (int kt2 = 0; kt2 < 8; ++kt2) {
      v8s pa = *(const v8s*)&Pw[l15][kt2 * 32 + lg8];
#pragma unroll
      for (int ct = 0; ct < 8; ++ct) {
        v8s bv = *(const v8s*)(KcT + vtb + (size_t)(ct * 16 + l15) * 256 + kt2 * 32 + lg8);
        oacc[ct] = MFMA16(pa, bv, oacc[ct]);
      }
    }
    v4f inv;
#pragma unroll
    for (int r = 0; r < 4; ++r) inv[r] = 1.0f / ssum[r];
#pragma unroll
    for (int ct = 0; ct < 8; ++ct)
#pragma unroll
      for (int r = 0; r < 4; ++r)
        AO[qb + (size_t)(nbase + lg4 + r) * 1024 + ct * 16 + l15] =
            (short)f2bf(oacc[ct][r] * inv[r]);
    __syncthreads();
  }
}

// --------------------------------------------------------------- out GEMM v3
__global__ __launch_bounds__(256) void k_gemm_out_v3(const short* __restrict__ AO,
                                                     const short* __restrict__ Wobf,
                                                     const float* __restrict__ bo,
                                                     float* __restrict__ out) {
  __shared__ short As[2][128][32];
  __shared__ short Bs[2][128][32];
  const int tid = threadIdx.x, lane = tid & 63, w = tid >> 6;
  const int m0 = blockIdx.x * 128, j0 = blockIdx.y * 128;
  const int wr = (w >> 1) * 64, wc = (w & 1) * 64;
  const int l15 = lane & 15, g = lane >> 4;
  const int sr = lane >> 2, sseg = lane & 3;

  v4f acc[4][4];
#pragma unroll
  for (int i = 0; i < 4; ++i)
#pragma unroll
    for (int j = 0; j < 4; ++j) acc[i][j] = (v4f)0.0f;

  auto stage = [&](int buf, int k0) {
#pragma unroll
    for (int q0 = 0; q0 < 2; ++q0) {
      const int rblk = (w * 2 + q0) << 4, r = rblk + sr;
      const int co = ((sseg ^ (r >> 1)) & 3) << 3;
      gld16(&As[buf][rblk][0], AO + (size_t)(m0 + r) * 1024 + k0 + co);
      gld16(&Bs[buf][rblk][0], Wobf + (size_t)(j0 + r) * 1024 + k0 + co);
    }
  };

  stage(0, 0);
#pragma unroll 1
  for (int p = 0, buf = 0; p < 32; ++p, buf ^= 1) {
    if (p + 1 < 32) stage(buf ^ 1, (p + 1) * 32);
    if (p < 31) { WAITV(4); } else { WAITV(0); }
    SBAR();
    v8s af[4], bf4[4];
#pragma unroll
    for (int mi = 0; mi < 4; ++mi)
      af[mi] = *frag_ptr(&As[buf][0][0], wr + mi * 16 + l15, g);
#pragma unroll
    for (int ni = 0; ni < 4; ++ni)
      bf4[ni] = *frag_ptr(&Bs[buf][0][0], wc + ni * 16 + l15, g);
#pragma unroll
    for (int ni = 0; ni < 4; ++ni)
#pragma unroll
      for (int mi = 0; mi < 4; ++mi)
        acc[mi][ni] = MFMA16(af[mi], bf4[ni], acc[mi][ni]);
    SBAR();
  }
  const int rbase = (lane >> 4) * 4;
#pragma unroll
  for (int mi = 0; mi < 4; ++mi)
#pragma unroll
    for (int ni = 0; ni < 4; ++ni) {
      const int col = j0 + wc + ni * 16 + l15;
      const float bias = bo[col];
#pragma unroll
      for (int r = 0; r < 4; ++r) {
        const int row = m0 + wr + mi * 16 + rbase + r;
        out[(size_t)row * 1024 + col] = acc[mi][ni][r] + bias;
      }
    }
}

// ---------------------------------------------------------------------------
extern "C" void kernel_launch(void* const* d_in, const int* in_sizes, int n_in,
                              void* d_out, int out_size, void* d_ws, size_t ws_size,
                              hipStream_t stream) {
  const float* x   = (const float*)d_in[0];
  const float* Wq  = (const float*)d_in[1];
  const float* Wk  = (const float*)d_in[2];
  const float* Wpk = (const float*)d_in[3];
  const float* bpk = (const float*)d_in[4];
  const float* Wo  = (const float*)d_in[5];
  const float* bo  = (const float*)d_in[6];

  // workspace layout (bytes) — identical to round-3/4-verified layout.
  const size_t OFF_WR   = 0;            // Wr   (32,256,4096) bf16   67,108,864
  const size_t OFF_XBF  = 67108864;     // xbf  (16384,1024)  bf16   33,554,432
  const size_t OFF_WQK  = 100663296;    // Wqk  (2048,1024)   bf16    4,194,304
  const size_t OFF_KPTP = 67108864;     // KpTp (4,1056,4096) bf16   34,603,008
  const size_t OFF_KCBF = 67108864;     // Kcbf (4,256,1024)  bf16    2,097,152
  const size_t OFF_KCT  = 69206016;     // KcT  (4,1024,256)  bf16    2,097,152
  const size_t OFF_WOBF = 101711872;    // Wobf (1024,1024)   bf16    2,097,152
  const size_t OFF_QBF  = 104857600;    // Qbf  (4,4096,1024) bf16   33,554,432
  const size_t OFF_KP   = 138412032;    // Kp/AO(4,4096,1024) bf16   33,554,432
  const size_t OFF_KC   = 171966464;    // Kc   (4,256,1024)  f32     4,194,304
  const size_t NEED     = 176160768;
  if (ws_size < NEED) return;

  char* ws = (char*)d_ws;
  short* Wr   = (short*)(ws + OFF_WR);
  short* xbf  = (short*)(ws + OFF_XBF);
  short* Wqk  = (short*)(ws + OFF_WQK);
  short* KpTp = (short*)(ws + OFF_KPTP);
  short* Kcbf = (short*)(ws + OFF_KCBF);
  short* KcT  = (short*)(ws + OFF_KCT);
  short* Wobf = (short*)(ws + OFF_WOBF);
  short* Qbf  = (short*)(ws + OFF_QBF);
  short* Kp   = (short*)(ws + OFF_KP);
  float* Kc   = (float*)(ws + OFF_KC);
  short* AO   = Kp;
  float* Ppart = (float*)d_out;   // 16 x 4 MB partials; dead before k_gemm_out
  float* outp = (float*)d_out;

  k_cvt<<<dim3(8192), dim3(256), 0, stream>>>(x, xbf, 16777216 / 8);
  k_cvt<<<dim3(512),  dim3(256), 0, stream>>>(Wq, Wqk, 1048576 / 8);
  k_cvt<<<dim3(512),  dim3(256), 0, stream>>>(Wk, Wqk + 1048576, 1048576 / 8);
  k_reorder_wpk<<<dim3(16384), dim3(256), 0, stream>>>(Wpk, Wr);
  k_gemm_qk_v3<<<dim3(128, 16), dim3(256), 0, stream>>>(xbf, Wqk, Qbf, Kp);
  k_transpose_pad<<<dim3(64, 16, 4), dim3(256), 0, stream>>>(Kp, KpTp);
  k_cvt<<<dim3(512), dim3(256), 0, stream>>>(Wo, Wobf, 1048576 / 8);
  k_zero_pad<<<dim3(256), dim3(256), 0, stream>>>(KpTp);
  k_conv_v4<<<dim3(256), dim3(512), 0, stream>>>(Wr, KpTp, Ppart);
  k_reduce_kc<<<dim3(1024), dim3(256), 0, stream>>>(Ppart, bpk, Kc);
  k_kc_post<<<dim3(4, 16, 4), dim3(256), 0, stream>>>(Kc, Kcbf, KcT);
  k_attn<<<dim3(32, 8, 4), dim3(256), 0, stream>>>(Qbf, Kcbf, KcT, AO);
  k_gemm_out_v3<<<dim3(128, 8), dim3(256), 0, stream>>>(AO, Wobf, bo, outp);
}

// Round 6
// 608.279 us; speedup vs baseline: 1.2182x; 1.0408x over previous
//
#include <hip/hip_runtime.h>

// ---------------------------------------------------------------------------
// ConvLinformerSelfAttention (MI355X/gfx950) — bf16 MFMA pipeline, round 6.
// conv v5: 256x128 tiles, grid 512 = 2 blocks/CU (cross-block TLP), 68KB LDS,
//          depth-2 gload_lds prefetch, 1 barrier + counted vmcnt per step.
// ---------------------------------------------------------------------------

typedef short v8s __attribute__((ext_vector_type(8)));   // 8 x bf16 bits
typedef float v4f __attribute__((ext_vector_type(4)));

#define MFMA16(a, b, c) __builtin_amdgcn_mfma_f32_16x16x32_bf16((a), (b), (c), 0, 0, 0)
#define WAITV(N) asm volatile("s_waitcnt vmcnt(" #N ")" ::: "memory")
#define SBAR() __builtin_amdgcn_s_barrier()

__device__ __forceinline__ unsigned short f2bf(float f) {
  unsigned int u = __float_as_uint(f);
  u += 0x7fffu + ((u >> 16) & 1u);   // RNE
  return (unsigned short)(u >> 16);
}

__device__ __forceinline__ v8s cvt8(float4 a, float4 b) {
  v8s v;
  v[0] = (short)f2bf(a.x); v[1] = (short)f2bf(a.y);
  v[2] = (short)f2bf(a.z); v[3] = (short)f2bf(a.w);
  v[4] = (short)f2bf(b.x); v[5] = (short)f2bf(b.y);
  v[6] = (short)f2bf(b.z); v[7] = (short)f2bf(b.w);
  return v;
}

// async global->LDS, 16B per lane; LDS dest = uniform base + lane*16.
__device__ __forceinline__ void gld16(void* lds, const void* g) {
  __builtin_amdgcn_global_load_lds(
      (const __attribute__((address_space(1))) void*)g,
      (__attribute__((address_space(3))) void*)lds, 16, 0, 0);
}

// Fragment pointer into a swizzled [rows][32] bf16 LDS tile.
// Storage: LDS(row, seg') holds global seg = seg' ^ ((row>>1)&3).
__device__ __forceinline__ const v8s* frag_ptr(const short* base, int row, int g) {
  return (const v8s*)(base + row * 32 + (((g ^ (row >> 1)) & 3) << 3));
}

// --------------------------------------------------------------- cvt f32->bf16
__global__ __launch_bounds__(256) void k_cvt(const float* __restrict__ src,
                                             short* __restrict__ dst, int n8) {
  const int i = blockIdx.x * 256 + threadIdx.x;
  if (i >= n8) return;
  const float4* s = (const float4*)src;
  ((v8s*)dst)[i] = cvt8(s[2 * i], s[2 * i + 1]);
}

// --------------------------------------------------------------- reorder Wpk
__global__ __launch_bounds__(256) void k_reorder_wpk(const float* __restrict__ Wpk,
                                                     short* __restrict__ Wr) {
  __shared__ short T[64][40];
  const int k  = blockIdx.x >> 6;
  const int n0 = (blockIdx.x & 63) << 6;
  const int tid = threadIdx.x;
  {
    const int i = tid >> 2, t0 = (tid & 3) << 3;
    const float* p = Wpk + ((size_t)k * 4096 + n0 + i) * 32 + t0;
    float4 a = *(const float4*)p, b = *(const float4*)(p + 4);
    *(v8s*)&T[i][t0] = cvt8(a, b);
  }
  __syncthreads();
  {
    const int t = tid >> 3, j0 = (tid & 7) << 3;
    v8s o;
#pragma unroll
    for (int q = 0; q < 8; ++q) o[q] = T[j0 + q][t];
    *(v8s*)(Wr + ((size_t)t * 256 + k) * 4096 + n0 + j0) = o;
  }
}

// --------------------------------------------------------------- zero pads
__global__ __launch_bounds__(256) void k_zero_pad(short* __restrict__ KpTp) {
  const int idx = blockIdx.x * 256 + threadIdx.x;   // < 65536
  const int ridx = idx >> 9, col8 = idx & 511;
  const int b = ridx >> 5, rr = ridx & 31;
  const int row = (rr < 15) ? rr : 1039 + (rr - 15);
  v8s z = {0, 0, 0, 0, 0, 0, 0, 0};
  *(v8s*)(KpTp + ((size_t)b * 1056 + row) * 4096 + col8 * 8) = z;
}

// --------------------------------------------------------------- QK GEMM v3
__global__ __launch_bounds__(256) void k_gemm_qk_v3(const short* __restrict__ xbf,
                                                    const short* __restrict__ Wqk,
                                                    short* __restrict__ Qbf,
                                                    short* __restrict__ Kp) {
  __shared__ short As[2][128][32];
  __shared__ short Bs[2][128][32];
  const int tid = threadIdx.x, lane = tid & 63, w = tid >> 6;
  const int m0 = blockIdx.x * 128, j0 = blockIdx.y * 128;
  const int wr = (w >> 1) * 64, wc = (w & 1) * 64;
  const int l15 = lane & 15, g = lane >> 4;
  const int sr = lane >> 2, sseg = lane & 3;

  v4f acc[4][4];
#pragma unroll
  for (int i = 0; i < 4; ++i)
#pragma unroll
    for (int j = 0; j < 4; ++j) acc[i][j] = (v4f)0.0f;

  auto stage = [&](int buf, int k0) {
#pragma unroll
    for (int q0 = 0; q0 < 2; ++q0) {
      const int rblk = (w * 2 + q0) << 4, r = rblk + sr;
      const int co = ((sseg ^ (r >> 1)) & 3) << 3;
      gld16(&As[buf][rblk][0], xbf + (size_t)(m0 + r) * 1024 + k0 + co);
      gld16(&Bs[buf][rblk][0], Wqk + (size_t)(j0 + r) * 1024 + k0 + co);
    }
  };

  stage(0, 0);
#pragma unroll 1
  for (int p = 0, buf = 0; p < 32; ++p, buf ^= 1) {
    if (p + 1 < 32) stage(buf ^ 1, (p + 1) * 32);
    if (p < 31) { WAITV(4); } else { WAITV(0); }
    SBAR();
    v8s af[4], bf4[4];
#pragma unroll
    for (int mi = 0; mi < 4; ++mi)
      af[mi] = *frag_ptr(&As[buf][0][0], wr + mi * 16 + l15, g);
#pragma unroll
    for (int ni = 0; ni < 4; ++ni)
      bf4[ni] = *frag_ptr(&Bs[buf][0][0], wc + ni * 16 + l15, g);
#pragma unroll
    for (int ni = 0; ni < 4; ++ni)
#pragma unroll
      for (int mi = 0; mi < 4; ++mi)
        acc[mi][ni] = MFMA16(af[mi], bf4[ni], acc[mi][ni]);
    SBAR();
  }
  const int rbase = (lane >> 4) * 4;
#pragma unroll
  for (int mi = 0; mi < 4; ++mi)
#pragma unroll
    for (int ni = 0; ni < 4; ++ni) {
      const int col = j0 + wc + ni * 16 + l15;
      short* dst = (col < 1024) ? Qbf : Kp;
      const int cj = (col < 1024) ? col : col - 1024;
#pragma unroll
      for (int r = 0; r < 4; ++r) {
        const int row = m0 + wr + mi * 16 + rbase + r;
        dst[(size_t)row * 1024 + cj] = (short)f2bf(acc[mi][ni][r]);
      }
    }
}

// --------------------------------------------------------------- transpose+pad
__global__ __launch_bounds__(256) void k_transpose_pad(const short* __restrict__ src,
                                                       short* __restrict__ dst) {
  __shared__ short T[64][72];
  const int r0 = blockIdx.x * 64, c0 = blockIdx.y * 64, b = blockIdx.z;
  const int tid = threadIdx.x;
  {
    const int i = tid >> 2, q = (tid & 3) << 4;
    const short* ps = src + ((size_t)b * 4096 + r0 + i) * 1024 + c0 + q;
    *(v8s*)&T[i][q]     = *(const v8s*)ps;
    *(v8s*)&T[i][q + 8] = *(const v8s*)(ps + 8);
  }
  __syncthreads();
  {
    const int j = tid >> 2, p = (tid & 3) << 4;
    v8s o0, o1;
#pragma unroll
    for (int t = 0; t < 8; ++t) o0[t] = T[p + t][j];
#pragma unroll
    for (int t = 0; t < 8; ++t) o1[t] = T[p + 8 + t][j];
    short* pd = dst + ((size_t)b * 1056 + 15 + c0 + j) * 4096 + r0 + p;
    *(v8s*)pd = o0;
    *(v8s*)(pd + 8) = o1;
  }
}

// --------------------------------------------------------------- conv GEMM v5
// P[ns][b][kch 256][d-window 128] = sum_{t,n in ns-chunk} Wr x shifted(KpTp)
// grid 512 = ns(16) x b(4) x nt(8); 512 thr, 8 waves (4M x 2N); 2 blocks/CU.
__global__ __launch_bounds__(512, 4) void k_conv_v5(const short* __restrict__ Wr,
                                                    const short* __restrict__ KpTp,
                                                    float* __restrict__ Pq) {
  __shared__ short A[3][256][32];    // 48 KB: t-plane A tiles, triple buffer
  __shared__ short Kt[2][160][32];   // 20 KB: halo'd KpTp (159 used rows), dbuf
  const int bid = blockIdx.x;
  // 32 blocks sharing one A-stream (same ns) share bid%8 -> same XCD L2.
  const int ns = (bid & 7) | (((bid >> 8) & 1) << 3);
  const int j  = (bid >> 3) & 31;
  const int b = j >> 3, nt = j & 7;
  const int D0 = nt * 128;
  const int nbase = ns * 256;
  const int tid = threadIdx.x, lane = tid & 63, w = tid >> 6;
  const int wm = (w >> 1) * 64, wn = (w & 1) * 64;
  const int l15 = lane & 15, g = lane >> 4;
  const int lr = lane >> 2, lseg = lane & 3;
  const short* KpTb = KpTp + (size_t)b * 1056 * 4096;

  v4f acc[4][4];
#pragma unroll
  for (int mi = 0; mi < 4; ++mi)
#pragma unroll
    for (int ni = 0; ni < 4; ++ni) acc[mi][ni] = (v4f)0.0f;

  // stage one 128-row round of the A tile for step s2 (1 gld16/lane/round).
  auto stageA = [&](int buf, int s2, int q) {
    const int t2 = s2 & 31, c2 = s2 >> 5;
    const int rblk = q * 128 + w * 16;
    const int row = rblk + lr;
    const int sg = ((lseg ^ (row >> 1)) & 3) << 3;
    gld16(&A[buf][rblk][0],
          Wr + ((size_t)t2 * 256 + row) * 4096 + nbase + c2 * 32 + sg);
  };
  // Kt: 159 used rows. q=0: rows 0..127 (all waves); q=1: rows 128..159
  // (waves 0,1 only; row 159 clamped junk).
  auto stageKt = [&](int buf, int c1, int q) {
    const int rblk = q * 128 + w * 16;
    const int row = rblk + lr;
    const int srow = row < 159 ? row : 158;
    const int sg = ((lseg ^ (row >> 1)) & 3) << 3;
    gld16(&Kt[buf][rblk][0],
          KpTb + (size_t)(D0 + srow) * 4096 + nbase + c1 * 32 + sg);
  };

  // prologue: A(0), Kt(0), A(1); drain all but A(1)'s 2 rounds.
  stageA(0, 0, 0); stageA(0, 0, 1);
  stageKt(0, 0, 0);
  if (w < 2) stageKt(0, 0, 1);
  stageA(1, 1, 0); stageA(1, 1, 1);
  WAITV(2);
  SBAR();

  // Hazards per step s (buffers cycle s%3): RAW on A[s%3] covered by prev
  // step's WAITV (drains A(s)) + SBAR; WAR on gld16 target (s+2)%3=(s-1)%3
  // covered by prev step's end barrier (all waves' ds_reads of s-1 done).
  int ab = 0, pab = 2;
#pragma unroll 1
  for (int s = 0; s < 256; ++s) {
    const int t = s & 31, c = s >> 5;
    const short* Abp = &A[ab][0][0];
    const short* Ktp = &Kt[c & 1][0][0];
    v8s aq[4], bq[4];
#pragma unroll
    for (int mi = 0; mi < 4; ++mi)
      aq[mi] = *frag_ptr(Abp, wm + mi * 16 + l15, g);
#pragma unroll
    for (int ni = 0; ni < 4; ++ni)
      bq[ni] = *frag_ptr(Ktp, wn + ni * 16 + l15 + t, g);
    if (s + 2 < 256) { stageA(pab, s + 2, 0); stageA(pab, s + 2, 1); }
    const bool kt0 = (t == 26) && (c < 7);
    const bool kt1 = (t == 27) && (c < 7);
    if (kt0) stageKt((c + 1) & 1, c + 1, 0);
    if (kt1 && w < 2) stageKt((c + 1) & 1, c + 1, 1);
    __builtin_amdgcn_s_setprio(1);
#pragma unroll
    for (int ni = 0; ni < 4; ++ni)
#pragma unroll
      for (int mi = 0; mi < 4; ++mi)
        acc[mi][ni] = MFMA16(aq[mi], bq[ni], acc[mi][ni]);
    __builtin_amdgcn_s_setprio(0);
    // counted wait: drain A(s+1) and older (incl. old Kt); keep A(s+2)
    // (+ this step's Kt round) in flight. In-order vmcnt retirement.
    if (s < 254) {
      if (kt0 || kt1) { WAITV(3); } else { WAITV(2); }
    } else if (s == 254) {
      WAITV(0);
    }
    SBAR();
    pab = ab; ab = (ab == 2) ? 0 : ab + 1;
  }

  float* Pp = Pq + (size_t)(ns * 4 + b) * 262144;  // [256][1024] window
#pragma unroll
  for (int mi = 0; mi < 4; ++mi)
#pragma unroll
    for (int ni = 0; ni < 4; ++ni) {
      const int col = D0 + wn + ni * 16 + l15;
#pragma unroll
      for (int r = 0; r < 4; ++r)
        Pp[(size_t)(wm + mi * 16 + g * 4 + r) * 1024 + col] = acc[mi][ni][r];
    }
}

// --------------------------------------------------------------- reduce Kc
// Kc[i] = bpk[k] + sum_{ns<16} P[ns][i], i over (4,256,1024). grid 1024x256.
__global__ __launch_bounds__(256) void k_reduce_kc(const float* __restrict__ P,
                                                   const float* __restrict__ bpk,
                                                   float* __restrict__ Kc) {
  const int i = (blockIdx.x * 256 + threadIdx.x) * 4;  // < 4*256*1024
  const float bias = bpk[(i >> 10) & 255];
  float4 s; s.x = bias; s.y = bias; s.z = bias; s.w = bias;
#pragma unroll
  for (int ns = 0; ns < 16; ++ns) {
    float4 v = *(const float4*)(P + (size_t)ns * 1048576 + i);
    s.x += v.x; s.y += v.y; s.z += v.z; s.w += v.w;
  }
  *(float4*)(Kc + i) = s;
}

// --------------------------------------------------------------- Kc post
__global__ __launch_bounds__(256) void k_kc_post(const float* __restrict__ Kc,
                                                 short* __restrict__ Kcbf,
                                                 short* __restrict__ KcT) {
  __shared__ short T[64][72];
  const int k0 = blockIdx.x * 64, d0 = blockIdx.y * 64, b = blockIdx.z;
  const int tid = threadIdx.x;
  {
    const int i = tid >> 2, q = (tid & 3) << 4;
    const float* ps = Kc + (size_t)(b * 256 + k0 + i) * 1024 + d0 + q;
    float4 f0 = *(const float4*)ps,       f1 = *(const float4*)(ps + 4);
    float4 f2 = *(const float4*)(ps + 8), f3 = *(const float4*)(ps + 12);
    v8s v0 = cvt8(f0, f1), v1 = cvt8(f2, f3);
    *(v8s*)&T[i][q] = v0;
    *(v8s*)&T[i][q + 8] = v1;
    short* pc = Kcbf + (size_t)(b * 256 + k0 + i) * 1024 + d0 + q;
    *(v8s*)pc = v0;
    *(v8s*)(pc + 8) = v1;
  }
  __syncthreads();
  {
    const int j = tid >> 2, p = (tid & 3) << 4;
    v8s o0, o1;
#pragma unroll
    for (int t = 0; t < 8; ++t) o0[t] = T[p + t][j];
#pragma unroll
    for (int t = 0; t < 8; ++t) o1[t] = T[p + 8 + t][j];
    short* pd = KcT + (size_t)(b * 1024 + d0 + j) * 256 + k0 + p;
    *(v8s*)pd = o0;
    *(v8s*)(pd + 8) = o1;
  }
}

// --------------------------------------------------------------- attention
__global__ __launch_bounds__(256) void k_attn(const short* __restrict__ Qbf,
                                              const short* __restrict__ Kcbf,
                                              const short* __restrict__ KcT,
                                              short* __restrict__ AO) {
  __shared__ short P[4][16][264];
  const int nt = blockIdx.x, h = blockIdx.y, b = blockIdx.z;
  const int tid = threadIdx.x, lane = tid & 63, w = tid >> 6;
  const int l15 = lane & 15, lg4 = (lane >> 4) * 4, lg8 = (lane >> 4) * 8;
  const float scale = 0.08838834764831845f;
  const size_t qb  = (size_t)b * 4096 * 1024 + (size_t)h * 128;
  const size_t kb  = (size_t)b * 256 * 1024 + (size_t)h * 128;
  const size_t vtb = ((size_t)b * 1024 + (size_t)h * 128) * 256;
  short (*Pw)[264] = P[w];
  const int n_wave = nt * 128 + w * 32;

#pragma unroll 1
  for (int half = 0; half < 2; ++half) {
    const int nbase = n_wave + half * 16;
    v8s aq[4];
#pragma unroll
    for (int kt = 0; kt < 4; ++kt)
      aq[kt] = *(const v8s*)(Qbf + qb + (size_t)(nbase + l15) * 1024 + kt * 32 + lg8);

    v4f dacc[16];
#pragma unroll
    for (int ct = 0; ct < 16; ++ct) dacc[ct] = (v4f)0.0f;
#pragma unroll 1
    for (int kt = 0; kt < 4; ++kt) {
#pragma unroll
      for (int ct = 0; ct < 16; ++ct) {
        v8s bk = *(const v8s*)(Kcbf + kb + (size_t)(ct * 16 + l15) * 1024 + kt * 32 + lg8);
        dacc[ct] = MFMA16(aq[kt], bk, dacc[ct]);
      }
    }
#pragma unroll
    for (int ct = 0; ct < 16; ++ct) dacc[ct] = dacc[ct] * scale;
    v4f m4 = dacc[0];
#pragma unroll
    for (int ct = 1; ct < 16; ++ct)
#pragma unroll
      for (int r = 0; r < 4; ++r) m4[r] = fmaxf(m4[r], dacc[ct][r]);
#pragma unroll
    for (int off = 1; off < 16; off <<= 1)
#pragma unroll
      for (int r = 0; r < 4; ++r) m4[r] = fmaxf(m4[r], __shfl_xor(m4[r], off, 64));
    v4f ssum = (v4f)0.0f;
#pragma unroll
    for (int ct = 0; ct < 16; ++ct)
#pragma unroll
      for (int r = 0; r < 4; ++r) {
        const float e = __expf(dacc[ct][r] - m4[r]);
        ssum[r] += e;
        Pw[lg4 + r][ct * 16 + l15] = (short)f2bf(e);
      }
#pragma unroll
    for (int off = 1; off < 16; off <<= 1)
#pragma unroll
      for (int r = 0; r < 4; ++r) ssum[r] += __shfl_xor(ssum[r], off, 64);
    __syncthreads();

    v4f oacc[8];
#pragma unroll
    for (int ct = 0; ct < 8; ++ct) oacc[ct] = (v4f)0.0f;
#pragma unroll 1
    for (int kt2 = 0; kt2 < 8; ++kt2) {
      v8s pa = *(const v8s*)&Pw[l15][kt2 * 32 + lg8];
#pragma unroll
      for (int ct = 0; ct < 8; ++ct) {
        v8s bv = *(const v8s*)(KcT + vtb + (size_t)(ct * 16 + l15) * 256 + kt2 * 32 + lg8);
        oacc[ct] = MFMA16(pa, bv, oacc[ct]);
      }
    }
    v4f inv;
#pragma unroll
    for (int r = 0; r < 4; ++r) inv[r] = 1.0f / ssum[r];
#pragma unroll
    for (int ct = 0; ct < 8; ++ct)
#pragma unroll
      for (int r = 0; r < 4; ++r)
        AO[qb + (size_t)(nbase + lg4 + r) * 1024 + ct * 16 + l15] =
            (short)f2bf(oacc[ct][r] * inv[r]);
    __syncthreads();
  }
}

// --------------------------------------------------------------- out GEMM v3
__global__ __launch_bounds__(256) void k_gemm_out_v3(const short* __restrict__ AO,
                                                     const short* __restrict__ Wobf,
                                                     const float* __restrict__ bo,
                                                     float* __restrict__ out) {
  __shared__ short As[2][128][32];
  __shared__ short Bs[2][128][32];
  const int tid = threadIdx.x, lane = tid & 63, w = tid >> 6;
  const int m0 = blockIdx.x * 128, j0 = blockIdx.y * 128;
  const int wr = (w >> 1) * 64, wc = (w & 1) * 64;
  const int l15 = lane & 15, g = lane >> 4;
  const int sr = lane >> 2, sseg = lane & 3;

  v4f acc[4][4];
#pragma unroll
  for (int i = 0; i < 4; ++i)
#pragma unroll
    for (int j = 0; j < 4; ++j) acc[i][j] = (v4f)0.0f;

  auto stage = [&](int buf, int k0) {
#pragma unroll
    for (int q0 = 0; q0 < 2; ++q0) {
      const int rblk = (w * 2 + q0) << 4, r = rblk + sr;
      const int co = ((sseg ^ (r >> 1)) & 3) << 3;
      gld16(&As[buf][rblk][0], AO + (size_t)(m0 + r) * 1024 + k0 + co);
      gld16(&Bs[buf][rblk][0], Wobf + (size_t)(j0 + r) * 1024 + k0 + co);
    }
  };

  stage(0, 0);
#pragma unroll 1
  for (int p = 0, buf = 0; p < 32; ++p, buf ^= 1) {
    if (p + 1 < 32) stage(buf ^ 1, (p + 1) * 32);
    if (p < 31) { WAITV(4); } else { WAITV(0); }
    SBAR();
    v8s af[4], bf4[4];
#pragma unroll
    for (int mi = 0; mi < 4; ++mi)
      af[mi] = *frag_ptr(&As[buf][0][0], wr + mi * 16 + l15, g);
#pragma unroll
    for (int ni = 0; ni < 4; ++ni)
      bf4[ni] = *frag_ptr(&Bs[buf][0][0], wc + ni * 16 + l15, g);
#pragma unroll
    for (int ni = 0; ni < 4; ++ni)
#pragma unroll
      for (int mi = 0; mi < 4; ++mi)
        acc[mi][ni] = MFMA16(af[mi], bf4[ni], acc[mi][ni]);
    SBAR();
  }
  const int rbase = (lane >> 4) * 4;
#pragma unroll
  for (int mi = 0; mi < 4; ++mi)
#pragma unroll
    for (int ni = 0; ni < 4; ++ni) {
      const int col = j0 + wc + ni * 16 + l15;
      const float bias = bo[col];
#pragma unroll
      for (int r = 0; r < 4; ++r) {
        const int row = m0 + wr + mi * 16 + rbase + r;
        out[(size_t)row * 1024 + col] = acc[mi][ni][r] + bias;
      }
    }
}

// ---------------------------------------------------------------------------
extern "C" void kernel_launch(void* const* d_in, const int* in_sizes, int n_in,
                              void* d_out, int out_size, void* d_ws, size_t ws_size,
                              hipStream_t stream) {
  const float* x   = (const float*)d_in[0];
  const float* Wq  = (const float*)d_in[1];
  const float* Wk  = (const float*)d_in[2];
  const float* Wpk = (const float*)d_in[3];
  const float* bpk = (const float*)d_in[4];
  const float* Wo  = (const float*)d_in[5];
  const float* bo  = (const float*)d_in[6];

  // workspace layout (bytes) — identical to rounds 3-5 verified layout.
  const size_t OFF_WR   = 0;            // Wr   (32,256,4096) bf16   67,108,864
  const size_t OFF_XBF  = 67108864;     // xbf  (16384,1024)  bf16   33,554,432
  const size_t OFF_WQK  = 100663296;    // Wqk  (2048,1024)   bf16    4,194,304
  const size_t OFF_KPTP = 67108864;     // KpTp (4,1056,4096) bf16   34,603,008
  const size_t OFF_KCBF = 67108864;     // Kcbf (4,256,1024)  bf16    2,097,152
  const size_t OFF_KCT  = 69206016;     // KcT  (4,1024,256)  bf16    2,097,152
  const size_t OFF_WOBF = 101711872;    // Wobf (1024,1024)   bf16    2,097,152
  const size_t OFF_QBF  = 104857600;    // Qbf  (4,4096,1024) bf16   33,554,432
  const size_t OFF_KP   = 138412032;    // Kp/AO(4,4096,1024) bf16   33,554,432
  const size_t OFF_KC   = 171966464;    // Kc   (4,256,1024)  f32     4,194,304
  const size_t NEED     = 176160768;
  if (ws_size < NEED) return;

  char* ws = (char*)d_ws;
  short* Wr   = (short*)(ws + OFF_WR);
  short* xbf  = (short*)(ws + OFF_XBF);
  short* Wqk  = (short*)(ws + OFF_WQK);
  short* KpTp = (short*)(ws + OFF_KPTP);
  short* Kcbf = (short*)(ws + OFF_KCBF);
  short* KcT  = (short*)(ws + OFF_KCT);
  short* Wobf = (short*)(ws + OFF_WOBF);
  short* Qbf  = (short*)(ws + OFF_QBF);
  short* Kp   = (short*)(ws + OFF_KP);
  float* Kc   = (float*)(ws + OFF_KC);
  short* AO   = Kp;
  float* Ppart = (float*)d_out;   // 16 x 4 MB partials; dead before k_gemm_out
  float* outp = (float*)d_out;

  k_cvt<<<dim3(8192), dim3(256), 0, stream>>>(x, xbf, 16777216 / 8);
  k_cvt<<<dim3(512),  dim3(256), 0, stream>>>(Wq, Wqk, 1048576 / 8);
  k_cvt<<<dim3(512),  dim3(256), 0, stream>>>(Wk, Wqk + 1048576, 1048576 / 8);
  k_reorder_wpk<<<dim3(16384), dim3(256), 0, stream>>>(Wpk, Wr);
  k_gemm_qk_v3<<<dim3(128, 16), dim3(256), 0, stream>>>(xbf, Wqk, Qbf, Kp);
  k_transpose_pad<<<dim3(64, 16, 4), dim3(256), 0, stream>>>(Kp, KpTp);
  k_cvt<<<dim3(512), dim3(256), 0, stream>>>(Wo, Wobf, 1048576 / 8);
  k_zero_pad<<<dim3(256), dim3(256), 0, stream>>>(KpTp);
  k_conv_v5<<<dim3(512), dim3(512), 0, stream>>>(Wr, KpTp, Ppart);
  k_reduce_kc<<<dim3(1024), dim3(256), 0, stream>>>(Ppart, bpk, Kc);
  k_kc_post<<<dim3(4, 16, 4), dim3(256), 0, stream>>>(Kc, Kcbf, KcT);
  k_attn<<<dim3(32, 8, 4), dim3(256), 0, stream>>>(Qbf, Kcbf, KcT, AO);
  k_gemm_out_v3<<<dim3(128, 8), dim3(256), 0, stream>>>(AO, Wobf, bo, outp);
}